// Round 7
// baseline (397.935 us; speedup 1.0000x reference)
//
#include <hip/hip_runtime.h>

#define ALPHA 0.9f
#define BETA  0.8f
#define XS 36960   // padded row stride for x and w1p

typedef _Float16 f16;
typedef _Float16 f16x8 __attribute__((ext_vector_type(8)));
typedef float f32x4 __attribute__((ext_vector_type(4)));
typedef unsigned int u32;

// async global->LDS DMA, 16B per lane: per-lane global src, wave-uniform LDS
// base + lane*16 dest (m97 pattern).
#define GLOAD_LDS16(gsrc, ldst)                                        \
  __builtin_amdgcn_global_load_lds(                                    \
      (const __attribute__((address_space(1))) void*)(gsrc),           \
      (__attribute__((address_space(3))) void*)(ldst), 16, 0, 0)

// de-interleave (h,l)-pair dwords: hpair = h1<<16|h0, lpair = l1<<16|l0
__device__ inline u32 hpair(u32 d0, u32 d1) {
#if __has_builtin(__builtin_amdgcn_perm)
  return __builtin_amdgcn_perm(d1, d0, 0x05040100u);
#else
  return (d0 & 0xffffu) | (d1 << 16);
#endif
}
__device__ inline u32 lpair(u32 d0, u32 d1) {
#if __has_builtin(__builtin_amdgcn_perm)
  return __builtin_amdgcn_perm(d1, d0, 0x07060302u);
#else
  return (d0 >> 16) | (d1 & 0xffff0000u);
#endif
}

// split fp32 -> packed (h,l) f16-pair dword (exact same h/l values as the
// old consumer-side split: h=f16(v), l=f16(v-h))
__device__ inline u32 pack_hl(float v) {
  f16 h = (f16)v;
  f16 l = (f16)(v - (float)h);
  return (u32)__builtin_bit_cast(unsigned short, h) |
         ((u32)__builtin_bit_cast(unsigned short, l) << 16);
}

// ---------------------------------------------------------------------------
// state: 128x3x224x224  conv1 32x3x8x8 s4 -> f1hl (hl-pair) 128x32x55x55
// f1hl -> conv2 64x32x4x4 s2 -> f2hl (hl-pair) 128x64x26x26
// f2hl -> conv3 64x64x3x3 s1 -> x rows fp32 (36864 + 90 history, pad 36960)
// Convs: split-f16 MFMA (hi+lo, 3 MFMAs/product, fp32-quality: absmax 0.0).
// r15: conv1 = r13 restore (51.7us; r14's counted-vmcnt pipeline cut
//   occupancy 49->27% and regressed to 72.7us -> conv time tracks resident
//   waves, i.e. memory-queue-bound, not per-wave-MLP-bound).
//   convhl: double-buffered B -> ONE barrier per K-step (halves the
//   queue-drain rounds); A fragments in register double-buffer loaded direct
//   from global (same addresses as old cooperative stage, no LDS trip).
//   reduce_p: 32 loads in flight (order-preserving), grid 256x64.
// r16: identical to r15 resubmission (round 6 was GPUAcquisitionTimeout,
//   kernel never ran).
// ---------------------------------------------------------------------------

// Split conv weights into f16 hi/lo pairs; conv3 padded [oc][c][kh][4]
// (kw=3 -> 0). Repack w2 (256x128) -> w2q[k4][j] float4 columns.
__global__ __launch_bounds__(256) void prep_weights_kernel(
    const float* __restrict__ cw1, const float* __restrict__ cw2,
    const float* __restrict__ cw3, const float* __restrict__ w2,
    f16* __restrict__ w1h, f16* __restrict__ w1l,
    f16* __restrict__ w2h, f16* __restrict__ w2l,
    f16* __restrict__ w3h, f16* __restrict__ w3l,
    float* __restrict__ w2q) {
  int i = blockIdx.x * 256 + threadIdx.x;   // grid covers 49152
  if (i < 6144)  { float v = cw1[i]; f16 h = (f16)v; w1h[i] = h; w1l[i] = (f16)(v - (float)h); }
  if (i < 32768) { float v = cw2[i]; f16 h = (f16)v; w2h[i] = h; w2l[i] = (f16)(v - (float)h); }
  if (i < 49152) {
    int oc = i / 768, r = i % 768;
    int c = r / 12, rr = r % 12, kh = rr >> 2, kw = rr & 3;
    float v = (kw < 3) ? cw3[oc * 576 + c * 9 + kh * 3 + kw] : 0.f;
    f16 h = (f16)v; w3h[i] = h; w3l[i] = (f16)(v - (float)h);
  }
  if (i < 32768) {   // w2[j][k] -> w2q[(k4*256 + j)*4 + e]
    int j = i >> 7, k = i & 127;
    w2q[((k >> 2) * 256 + j) * 4 + (k & 3)] = w2[i];
  }
}

// Copy w1 (128 x 36954) into padded rows (128 x 36960), zero tail.
__global__ __launch_bounds__(256) void pad_w1_kernel(
    const float* __restrict__ w1, float* __restrict__ w1p) {
  int i = blockIdx.x * 256 + threadIdx.x;   // float2 slots: 128 * 18480
  if (i < 128 * 18480) {
    int j = i / 18480, c = i - j * 18480;
    float2 v;
    if (c < 18477) v = *(const float2*)&w1[(size_t)j * 36954 + c * 2];
    else v = make_float2(0.f, 0.f);
    *(float2*)&w1p[(size_t)j * XS + c * 2] = v;
  }
}

// ---------------------------------------------------------------------------
// conv1 (r13): 16x16x32 MFMA layouts (HW-verified): A[m=lane&15][k=quad*8+j],
// B[k=quad*8+j][n=lane&15], C col=lane&15 row=quad*4+reg.
// B slot s (0..511): holds B[k=kt*32+((s>>4)&3)*8+j][npos=(s>>6)*16+(s&15)],
// raw fp32, staged by global_load_lds. Gathers 16B-aligned. Convert to
// split-f16 at fragment read (WOC=1: each slot read once).
// ---------------------------------------------------------------------------
__global__ __launch_bounds__(256) void conv1_kernel(
    const float* __restrict__ in, const f16* __restrict__ wh,
    const f16* __restrict__ wl, const float* __restrict__ bias,
    u32* __restrict__ out) {
  constexpr int K = 192, KCH = 6, OW = 55, OHW = 3025, NPB = 128;
  __shared__ __attribute__((aligned(16))) f16 Ah[2 * 512], Al[2 * 512]; // 4KB
  __shared__ __attribute__((aligned(16))) float Bf[8 * 512];            // 16KB

  const int n = blockIdx.y, pos0 = blockIdx.x * NPB;
  const int t = threadIdx.x;
  const int w = t >> 6, lane = t & 63, quad = lane >> 4, l16 = lane & 15;
  const float* __restrict__ inb = in + (size_t)n * 3 * 224 * 224;

  // staging invariants: rq = filter-row offset within kt (same for both si)
  const int rq = (t >> 4) & 3;
  int base[2];
#pragma unroll
  for (int si = 0; si < 2; ++si) {
    int s = t + si * 256;
    int pos = pos0 + (s >> 6) * 16 + (s & 15);
    if (pos > OHW - 1) pos = OHW - 1;      // clamp (store masked later)
    int oh = pos / OW, ow = pos - oh * OW;
    base[si] = oh * 4 * 224 + ow * 4;
  }
  // A slot (t<128): oc am, k offset ak
  const int am = (t >> 6) * 16 + (t & 15);
  const int ak = ((t >> 4) & 3) * 8;

  int posv[2];
#pragma unroll
  for (int ntl = 0; ntl < 2; ++ntl)
    posv[ntl] = pos0 + (w * 2 + ntl) * 16 + l16;

  f32x4 acc[2][2] = {};

  for (int kt = 0; kt < KCH; ++kt) {
    __syncthreads();
    if (t < 128) {   // stage weights (tiny, plain)
      *(f16x8*)&Ah[t * 8] = *(const f16x8*)&wh[am * K + kt * 32 + ak];
      *(f16x8*)&Al[t * 8] = *(const f16x8*)&wl[am * K + kt * 32 + ak];
    }
    {  // async B staging: 4 global_load_lds per wave
      int r = kt * 4 + rq;
      int c = r >> 3, kh = r & 7;
      int rowoff = c * 50176 + kh * 224;
#pragma unroll
      for (int si = 0; si < 2; ++si)
#pragma unroll
        for (int half = 0; half < 2; ++half)
          GLOAD_LDS16(inb + rowoff + base[si] + half * 4,
                      &Bf[(si * 4 + w) * 512 + half * 256]);
    }
    __syncthreads();   // drains vmcnt: B in LDS, A visible

    f16x8 ah0 = *(const f16x8*)&Ah[0 * 512 + lane * 8];
    f16x8 ah1 = *(const f16x8*)&Ah[1 * 512 + lane * 8];
    f16x8 al0 = *(const f16x8*)&Al[0 * 512 + lane * 8];
    f16x8 al1 = *(const f16x8*)&Al[1 * 512 + lane * 8];
    f16x8 bh[2], bl[2];
#pragma unroll
    for (int ntl = 0; ntl < 2; ++ntl) {
      const float* bp = &Bf[(w * 2 + ntl) * 512 + lane * 4];
      float4 v0 = *(const float4*)bp;
      float4 v1 = *(const float4*)(bp + 256);
      float vv[8] = {v0.x, v0.y, v0.z, v0.w, v1.x, v1.y, v1.z, v1.w};
#pragma unroll
      for (int e = 0; e < 8; ++e) {
        f16 h = (f16)vv[e];
        bh[ntl][e] = h;
        bl[ntl][e] = (f16)(vv[e] - (float)h);
      }
    }
    acc[0][0] = __builtin_amdgcn_mfma_f32_16x16x32_f16(ah0, bh[0], acc[0][0], 0, 0, 0);
    acc[0][0] = __builtin_amdgcn_mfma_f32_16x16x32_f16(ah0, bl[0], acc[0][0], 0, 0, 0);
    acc[0][0] = __builtin_amdgcn_mfma_f32_16x16x32_f16(al0, bh[0], acc[0][0], 0, 0, 0);
    acc[1][0] = __builtin_amdgcn_mfma_f32_16x16x32_f16(ah1, bh[0], acc[1][0], 0, 0, 0);
    acc[1][0] = __builtin_amdgcn_mfma_f32_16x16x32_f16(ah1, bl[0], acc[1][0], 0, 0, 0);
    acc[1][0] = __builtin_amdgcn_mfma_f32_16x16x32_f16(al1, bh[0], acc[1][0], 0, 0, 0);
    acc[0][1] = __builtin_amdgcn_mfma_f32_16x16x32_f16(ah0, bh[1], acc[0][1], 0, 0, 0);
    acc[0][1] = __builtin_amdgcn_mfma_f32_16x16x32_f16(ah0, bl[1], acc[0][1], 0, 0, 0);
    acc[0][1] = __builtin_amdgcn_mfma_f32_16x16x32_f16(al0, bh[1], acc[0][1], 0, 0, 0);
    acc[1][1] = __builtin_amdgcn_mfma_f32_16x16x32_f16(ah1, bh[1], acc[1][1], 0, 0, 0);
    acc[1][1] = __builtin_amdgcn_mfma_f32_16x16x32_f16(ah1, bl[1], acc[1][1], 0, 0, 0);
    acc[1][1] = __builtin_amdgcn_mfma_f32_16x16x32_f16(al1, bh[1], acc[1][1], 0, 0, 0);
  }

#pragma unroll
  for (int mtl = 0; mtl < 2; ++mtl)
#pragma unroll
    for (int ntl = 0; ntl < 2; ++ntl)
#pragma unroll
      for (int r = 0; r < 4; ++r) {
        int oc  = mtl * 16 + quad * 4 + r;
        int pos = posv[ntl];
        if (pos < OHW) {
          float v = acc[mtl][ntl][r] + bias[oc];
          v = v > 0.f ? v : 0.f;
          out[((size_t)n * 32 + oc) * OHW + pos] = pack_hl(v);
        }
      }
}

// ---------------------------------------------------------------------------
// conv2/conv3 (r15): input packed (h,l)-pair dwords. B double-buffered in
// LDS -> ONE barrier per K-step (was 2): stage(buf k&1) -> barrier ->
// compute(buf k&1); next stage hits the other buffer, so no wave can
// overwrite a buffer still being read (full-barrier ordering). A fragments
// in a register ping-pong (A0/A1), loaded direct from global each K-step --
// identical addresses to the old cooperative stage, minus the LDS round-trip.
// LDS total unchanged (16KB).
// ---------------------------------------------------------------------------
template<int IC, int KH, int KWP, int KWV, int S, int IH, int IW,
         int OW, int OHW, int OC, int NPB, bool OUT_X>
__global__ __launch_bounds__(256) void convhl_kernel(
    const u32* __restrict__ in, const f16* __restrict__ wh,
    const f16* __restrict__ wl, const float* __restrict__ bias,
    void* __restrict__ outv) {
  constexpr int K = IC * KH * KWP;      // 512 / 768
  constexpr int KCH = K / 32;           // 16 / 24 (even)
  __shared__ __attribute__((aligned(16))) u32 Bhl[2][2][256 * 4];   // 16KB

  const int n = blockIdx.y, pos0 = blockIdx.x * NPB;
  const int t = threadIdx.x;
  const int w = t >> 6, lane = t & 63, quad = lane >> 4, l16 = lane & 15;
  const int woc = w & 1, wpos = w >> 1;
  const u32* __restrict__ inb = in + (size_t)n * IC * IH * IW;

  // B slot s = t: npos = (t>>6)*16 + (t&15); k-rows kt*8 + rq + half
  int pos = pos0 + (t >> 6) * 16 + (t & 15);
  if (pos > OHW - 1) pos = OHW - 1;      // clamp (store masked later)
  int oh = pos / OW, ow = pos - oh * OW;
  const int ohS = oh * S, owS = ow * S;
  const int rq = ((t >> 4) & 3) * 2;

  // A direct-load bases: lane reads oc=(woc*2+mtl)*16+l16, k=kt*32+quad*8..
  const f16* __restrict__ wh0 = wh + (size_t)((woc * 2 + 0) * 16 + l16) * K;
  const f16* __restrict__ wh1 = wh + (size_t)((woc * 2 + 1) * 16 + l16) * K;
  const f16* __restrict__ wl0 = wl + (size_t)((woc * 2 + 0) * 16 + l16) * K;
  const f16* __restrict__ wl1 = wl + (size_t)((woc * 2 + 1) * 16 + l16) * K;

  int posv[2];
#pragma unroll
  for (int ntl = 0; ntl < 2; ++ntl)
    posv[ntl] = pos0 + (wpos * 2 + ntl) * 16 + l16;

  f32x4 acc[2][2] = {};

  auto STAGEB = [&](int kt, int buf) {
#pragma unroll
    for (int half = 0; half < 2; ++half) {
      int row = kt * 8 + rq + half;
      int c = row / KH, kh = row - c * KH;
      const u32* p = inb + ((size_t)c * IH + ohS + kh) * IW + owS;
      uint4 d;
      d.x = p[0]; d.y = p[1]; d.z = p[2];
      d.w = (KWV < KWP) ? 0u : p[3];       // conv3: padded kw=3 -> 0
      *(uint4*)&Bhl[buf][half][t * 4] = d;
    }
  };

  auto LOADA = [&](int kt, f16x8& h0, f16x8& h1, f16x8& l0, f16x8& l1) {
    h0 = *(const f16x8*)&wh0[kt * 32 + quad * 8];
    h1 = *(const f16x8*)&wh1[kt * 32 + quad * 8];
    l0 = *(const f16x8*)&wl0[kt * 32 + quad * 8];
    l1 = *(const f16x8*)&wl1[kt * 32 + quad * 8];
  };

  auto COMPUTE = [&](f16x8 ah0, f16x8 ah1, f16x8 al0, f16x8 al1, int buf) {
    f16x8 bh[2], bl[2];
#pragma unroll
    for (int ntl = 0; ntl < 2; ++ntl) {
      int sl = ((wpos * 2 + ntl) * 64 + lane) * 4;
      uint4 q0 = *(const uint4*)&Bhl[buf][0][sl];
      uint4 q1 = *(const uint4*)&Bhl[buf][1][sl];
      uint4 hv, lv;
      hv.x = hpair(q0.x, q0.y); lv.x = lpair(q0.x, q0.y);
      hv.y = hpair(q0.z, q0.w); lv.y = lpair(q0.z, q0.w);
      hv.z = hpair(q1.x, q1.y); lv.z = lpair(q1.x, q1.y);
      hv.w = hpair(q1.z, q1.w); lv.w = lpair(q1.z, q1.w);
      bh[ntl] = __builtin_bit_cast(f16x8, hv);
      bl[ntl] = __builtin_bit_cast(f16x8, lv);
    }
    acc[0][0] = __builtin_amdgcn_mfma_f32_16x16x32_f16(ah0, bh[0], acc[0][0], 0, 0, 0);
    acc[0][0] = __builtin_amdgcn_mfma_f32_16x16x32_f16(ah0, bl[0], acc[0][0], 0, 0, 0);
    acc[0][0] = __builtin_amdgcn_mfma_f32_16x16x32_f16(al0, bh[0], acc[0][0], 0, 0, 0);
    acc[1][0] = __builtin_amdgcn_mfma_f32_16x16x32_f16(ah1, bh[0], acc[1][0], 0, 0, 0);
    acc[1][0] = __builtin_amdgcn_mfma_f32_16x16x32_f16(ah1, bl[0], acc[1][0], 0, 0, 0);
    acc[1][0] = __builtin_amdgcn_mfma_f32_16x16x32_f16(al1, bh[0], acc[1][0], 0, 0, 0);
    acc[0][1] = __builtin_amdgcn_mfma_f32_16x16x32_f16(ah0, bh[1], acc[0][1], 0, 0, 0);
    acc[0][1] = __builtin_amdgcn_mfma_f32_16x16x32_f16(ah0, bl[1], acc[0][1], 0, 0, 0);
    acc[0][1] = __builtin_amdgcn_mfma_f32_16x16x32_f16(al0, bh[1], acc[0][1], 0, 0, 0);
    acc[1][1] = __builtin_amdgcn_mfma_f32_16x16x32_f16(ah1, bh[1], acc[1][1], 0, 0, 0);
    acc[1][1] = __builtin_amdgcn_mfma_f32_16x16x32_f16(ah1, bl[1], acc[1][1], 0, 0, 0);
    acc[1][1] = __builtin_amdgcn_mfma_f32_16x16x32_f16(al1, bh[1], acc[1][1], 0, 0, 0);
  };

  f16x8 A0h0, A0h1, A0l0, A0l1, A1h0, A1h1, A1l0, A1l1;
  LOADA(0, A0h0, A0h1, A0l0, A0l1);

#pragma unroll 1
  for (int kt = 0; kt < KCH; kt += 2) {
    STAGEB(kt, 0);
    LOADA(kt + 1, A1h0, A1h1, A1l0, A1l1);
    __syncthreads();
    COMPUTE(A0h0, A0h1, A0l0, A0l1, 0);
    STAGEB(kt + 1, 1);
    if (kt + 2 < KCH) LOADA(kt + 2, A0h0, A0h1, A0l0, A0l1);
    __syncthreads();
    COMPUTE(A1h0, A1h1, A1l0, A1l1, 1);
  }

#pragma unroll
  for (int mtl = 0; mtl < 2; ++mtl)
#pragma unroll
    for (int ntl = 0; ntl < 2; ++ntl)
#pragma unroll
      for (int r = 0; r < 4; ++r) {
        int oc = (woc * 2 + mtl) * 16 + quad * 4 + r;
        int p2 = posv[ntl];
        if (p2 < OHW) {
          float v = acc[mtl][ntl][r] + bias[oc];
          v = v > 0.f ? v : 0.f;
          if constexpr (OUT_X)
            ((float*)outv)[(size_t)n * XS + oc * OHW + p2] = v;
          else
            ((u32*)outv)[((size_t)n * OC + oc) * OHW + p2] = pack_hl(v);
        }
      }
}

// history -> x[:, 36864:36954], zero the pad to 36960
__global__ __launch_bounds__(256) void histpack_kernel(
    const float* __restrict__ h, float* __restrict__ x) {
  int i = blockIdx.x * 256 + threadIdx.x;
  if (i < 128 * 96) {
    int n = i / 96, k = i % 96;
    x[(size_t)n * XS + 36864 + k] = (k < 90) ? h[n * 90 + k] : 0.f;
  }
}

// FC1 (fp32): register-blocked split-K GEMM, 128b x 128j tile per block,
// thread owns 8x8 interleaved sub-tile. P[kt][b][j] deterministic partials.
#define FC1_KT 289
__global__ __launch_bounds__(256) void fc1_kernel(
    const float* __restrict__ x, const float* __restrict__ w1p,
    float* __restrict__ P) {
  int kt = blockIdx.x;        // 0..288
  int t  = threadIdx.x;
  int bq = t & 15, jq = t >> 4;
  __shared__ float xs[128 * 36];
  __shared__ float wsm[128 * 36];
  float acc[8][8];
#pragma unroll
  for (int bb = 0; bb < 8; ++bb)
#pragma unroll
    for (int jj = 0; jj < 8; ++jj) acc[bb][jj] = 0.f;

  int cs = t & 7;          // float4 column for staging (0..7)
  int rs = t >> 3;         // row base for staging (0..31), 4 passes
#pragma unroll 1
  for (int s = 0; s < 4; ++s) {
    int k0 = kt * 128 + s * 32;
    __syncthreads();
#pragma unroll
    for (int p = 0; p < 4; ++p) {
      int r = rs + p * 32;
      int gk = k0 + cs * 4;
      float4 xv, wv;
      if (gk < 36954) {
        xv = *(const float4*)&x[(size_t)r * XS + gk];
        wv = *(const float4*)&w1p[(size_t)r * XS + gk];
      } else {
        xv = make_float4(0.f, 0.f, 0.f, 0.f);
        wv = make_float4(0.f, 0.f, 0.f, 0.f);
      }
      *(float4*)&xs[r * 36 + cs * 4] = xv;
      *(float4*)&wsm[r * 36 + cs * 4] = wv;
    }
    __syncthreads();
#pragma unroll 1
    for (int kk = 0; kk < 32; kk += 4) {
      float4 xv[8], wv[8];
#pragma unroll
      for (int i = 0; i < 8; ++i)
        xv[i] = *(const float4*)&xs[(bq + 16 * i) * 36 + kk];
#pragma unroll
      for (int i = 0; i < 8; ++i)
        wv[i] = *(const float4*)&wsm[(jq + 16 * i) * 36 + kk];
#pragma unroll
      for (int bb = 0; bb < 8; ++bb)
#pragma unroll
        for (int jj = 0; jj < 8; ++jj) {
          acc[bb][jj] = fmaf(xv[bb].x, wv[jj].x, acc[bb][jj]);
          acc[bb][jj] = fmaf(xv[bb].y, wv[jj].y, acc[bb][jj]);
          acc[bb][jj] = fmaf(xv[bb].z, wv[jj].z, acc[bb][jj]);
          acc[bb][jj] = fmaf(xv[bb].w, wv[jj].w, acc[bb][jj]);
        }
    }
  }
  float* Pb = P + (size_t)kt * 16384;
#pragma unroll
  for (int bb = 0; bb < 8; ++bb)
#pragma unroll
    for (int jj = 0; jj < 8; ++jj)
      Pb[(bq + 16 * bb) * 128 + jq + 16 * jj] = acc[bb][jj];
}

// Reduce P over kt: h1s[b][j] = sum_kt P[kt][b][j] + b1[j].
// r15: 32 loads in flight per thread (order-preserving: per-accumulator
// add sequences identical to the old 4-accumulator loop), 1 wave/block x
// 256 blocks to engage all CUs. Was ~260KB chip-wide in flight -> ~1TB/s.
__global__ __launch_bounds__(64) void reduce_p_kernel(
    const float* __restrict__ P, const float* __restrict__ b1,
    float* __restrict__ h1s) {
  int idx = blockIdx.x * 64 + threadIdx.x;   // 0..16383
  int j = idx & 127;
  float a0 = 0.f, a1 = 0.f, a2 = 0.f, a3 = 0.f;
  int kt = 0;
  for (; kt + 31 < FC1_KT; kt += 32) {
    float v[32];
#pragma unroll
    for (int q = 0; q < 32; ++q)
      v[q] = P[(size_t)(kt + q) * 16384 + idx];
#pragma unroll
    for (int q = 0; q < 32; q += 4) {
      a0 += v[q]; a1 += v[q + 1]; a2 += v[q + 2]; a3 += v[q + 3];
    }
  }
  for (; kt + 3 < FC1_KT; kt += 4) {
    a0 += P[(size_t)(kt + 0) * 16384 + idx];
    a1 += P[(size_t)(kt + 1) * 16384 + idx];
    a2 += P[(size_t)(kt + 2) * 16384 + idx];
    a3 += P[(size_t)(kt + 3) * 16384 + idx];
  }
  for (; kt < FC1_KT; ++kt) a0 += P[(size_t)kt * 16384 + idx];
  h1s[idx] = ((a0 + a1) + (a2 + a3)) + b1[j];
}

// Recurrence: one block per batch row. w2 column in VGPRs (loaded once,
// 32 coalesced dwordx4); spk broadcast via LDS; w3 staged in LDS; layer3
// as 144-thread partials + 9-thread reduce. Critical path ~700 cyc/step.
__global__ __launch_bounds__(256, 1) void recur_kernel(
    const float* __restrict__ h1s,  // [128][128]
    const float4* __restrict__ w2q, // [32][256] float4 cols: w2q[k4*256+j]
    const float* __restrict__ b2,
    const float* __restrict__ w3,   // [9][256]
    const float* __restrict__ b3,
    float* __restrict__ out) {      // [128][9]
  int b = blockIdx.x;
  int t = threadIdx.x;
  __shared__ float spk1s[128];
  __shared__ float spk2s[256];
  __shared__ float w3s[9 * 256];
  __shared__ float part[9][16];
  float4 w2c[32];
#pragma unroll
  for (int k4 = 0; k4 < 32; ++k4) w2c[k4] = w2q[k4 * 256 + t];
  for (int i = t; i < 9 * 256; i += 256) w3s[i] = w3[i];
  float h1 = (t < 128) ? h1s[b * 128 + t] : 0.f;
  float mem1 = 0.f, syn1 = 0.f, mem2 = 0.f, syn2 = 0.f;
  float b2v = b2[t];
  float mem3 = 0.f, syn3 = 0.f, pot = 0.f;
  float b3v = (t < 9) ? b3[t] : 0.f;
  int j3 = t >> 4, p = t & 15;      // layer3 partial owners (t < 144)
  __syncthreads();                  // w3s ready

  for (int step = 0; step < 10; ++step) {
    if (t < 128) {
      syn1 = ALPHA * syn1 + h1;
      mem1 = BETA * mem1 + syn1;
      float s = (mem1 > 1.0f) ? 1.0f : 0.0f;
      mem1 -= s;
      spk1s[t] = s;
    }
    __syncthreads();
    float h2 = b2v;
#pragma unroll
    for (int k4 = 0; k4 < 32; ++k4) {
      float4 s = *(const float4*)&spk1s[k4 * 4];   // broadcast read
      h2 = fmaf(s.x, w2c[k4].x, h2);
      h2 = fmaf(s.y, w2c[k4].y, h2);
      h2 = fmaf(s.z, w2c[k4].z, h2);
      h2 = fmaf(s.w, w2c[k4].w, h2);
    }
    syn2 = ALPHA * syn2 + h2;
    mem2 = BETA * mem2 + syn2;
    float s2 = (mem2 > 1.0f) ? 1.0f : 0.0f;
    mem2 -= s2;
    spk2s[t] = s2;
    __syncthreads();
    if (t < 144) {
      float a = 0.f;
      const float* wr = &w3s[j3 * 256 + p * 16];
      const float* sp = &spk2s[p * 16];
#pragma unroll
      for (int e = 0; e < 16; ++e) a = fmaf(sp[e], wr[e], a);
      part[j3][p] = a;
    }
    __syncthreads();
    if (t < 9) {
      float a = b3v;
#pragma unroll
      for (int p2 = 0; p2 < 16; ++p2) a += part[t][p2];
      syn3 = ALPHA * syn3 + a;
      mem3 = BETA * mem3 + syn3;
      pot += mem3;
    }
  }
  if (t < 9) out[b * 9 + t] = pot * 0.1f;
}

extern "C" void kernel_launch(void* const* d_in, const int* in_sizes, int n_in,
                              void* d_out, int out_size, void* d_ws, size_t ws_size,
                              hipStream_t stream) {
  const float* state   = (const float*)d_in[0];
  const float* history = (const float*)d_in[1];
  const float* cw1 = (const float*)d_in[2];
  const float* cb1 = (const float*)d_in[3];
  const float* cw2 = (const float*)d_in[4];
  const float* cb2 = (const float*)d_in[5];
  const float* cw3 = (const float*)d_in[6];
  const float* cb3 = (const float*)d_in[7];
  const float* w1  = (const float*)d_in[8];
  const float* b1  = (const float*)d_in[9];
  const float* w2  = (const float*)d_in[10];
  const float* b2  = (const float*)d_in[11];
  const float* w3  = (const float*)d_in[12];
  const float* b3  = (const float*)d_in[13];
  float* out = (float*)d_out;
  char* ws = (char*)d_ws;

  // workspace (bytes), time-multiplexed:
  //  f1hl  [0, 49,561,600)              conv1 -> conv2  (hl-pair dwords)
  //    xb  [0, 18,923,520)              conv3 -> fc1    (f1hl dead)
  //    w1p [18,923,520, 37,847,040)     pad_w1 (after conv2) -> fc1
  //  f2hl  [49,561,600, 71,712,768)     conv2 -> conv3  (hl-pair dwords)
  //    P   [49,561,600, 68,501,504)     fc1 -> reduce   (f2hl dead)
  //  small weights [71,712,768, 72,261,632)
  u32*   f1hl = (u32*)(ws + 0);
  float* xb   = (float*)(ws + 0);
  float* w1p  = (float*)(ws + 18923520);
  u32*   f2hl = (u32*)(ws + 49561600);
  float* P    = (float*)(ws + 49561600);
  f16* wf1h = (f16*)(ws + 71712768);   // 12,288
  f16* wf1l = (f16*)(ws + 71725056);   // 12,288
  f16* wf2h = (f16*)(ws + 71737344);   // 65,536
  f16* wf2l = (f16*)(ws + 71802880);   // 65,536
  f16* wf3h = (f16*)(ws + 71868416);   // 98,304 (padded K=768)
  f16* wf3l = (f16*)(ws + 71966720);   // 98,304
  float* w2q = (float*)(ws + 72065024);  // 131,072
  float* h1s = (float*)(ws + 72196096);  // 65,536 (end 72,261,632)

  prep_weights_kernel<<<192, 256, 0, stream>>>(cw1, cw2, cw3, w2,
                                               wf1h, wf1l, wf2h, wf2l,
                                               wf3h, wf3l, w2q);
  // conv1: 224x224 -> 55x55(3025), OC=32, NPB=128, async-LDS staged (r13)
  conv1_kernel<<<dim3(24, 128), 256, 0, stream>>>(state, wf1h, wf1l, cb1, f1hl);
  // conv2: IC=32,KH=4,KWP=4,KWV=4,S=2, 55x55 -> 26x26(676), OC=64, NPB=64
  convhl_kernel<32, 4, 4, 4, 2, 55, 55, 26, 676, 64, 64, false>
      <<<dim3(11, 128), 256, 0, stream>>>(f1hl, wf2h, wf2l, cb2, (void*)f2hl);
  pad_w1_kernel<<<9240, 256, 0, stream>>>(w1, w1p);
  // conv3: IC=64,KH=3,KWP=4,KWV=3,S=1, 26x26 -> 24x24(576), OC=64, NPB=64 -> x
  convhl_kernel<64, 3, 4, 3, 1, 26, 26, 24, 576, 64, 64, true>
      <<<dim3(9, 128), 256, 0, stream>>>(f2hl, wf3h, wf3l, cb3, (void*)xb);
  histpack_kernel<<<48, 256, 0, stream>>>(history, xb);
  fc1_kernel<<<FC1_KT, 256, 0, stream>>>(xb, w1p, P);
  reduce_p_kernel<<<256, 64, 0, stream>>>(P, b1, h1s);
  recur_kernel<<<128, 256, 0, stream>>>(h1s, (const float4*)w2q, b2, w3, b3, out);
}

// Round 8
// 339.130 us; speedup vs baseline: 1.1734x; 1.1734x over previous
//
#include <hip/hip_runtime.h>

#define ALPHA 0.9f
#define BETA  0.8f
#define XS 36960   // padded row stride for x

typedef _Float16 f16;
typedef _Float16 f16x8 __attribute__((ext_vector_type(8)));
typedef float f32x4 __attribute__((ext_vector_type(4)));
typedef unsigned int u32;

// 16B load at only-4B-known alignment (w1 rows stride 36954 floats -> odd
// rows are 8B-aligned). Backend emits unaligned wide loads; same bytes.
struct F4 { float x, y, z, w; };   // alignof = 4

// async global->LDS DMA, 16B per lane: per-lane global src, wave-uniform LDS
// base + lane*16 dest (m97 pattern).
#define GLOAD_LDS16(gsrc, ldst)                                        \
  __builtin_amdgcn_global_load_lds(                                    \
      (const __attribute__((address_space(1))) void*)(gsrc),           \
      (__attribute__((address_space(3))) void*)(ldst), 16, 0, 0)

// de-interleave (h,l)-pair dwords: hpair = h1<<16|h0, lpair = l1<<16|l0
__device__ inline u32 hpair(u32 d0, u32 d1) {
#if __has_builtin(__builtin_amdgcn_perm)
  return __builtin_amdgcn_perm(d1, d0, 0x05040100u);
#else
  return (d0 & 0xffffu) | (d1 << 16);
#endif
}
__device__ inline u32 lpair(u32 d0, u32 d1) {
#if __has_builtin(__builtin_amdgcn_perm)
  return __builtin_amdgcn_perm(d1, d0, 0x07060302u);
#else
  return (d0 >> 16) | (d1 & 0xffff0000u);
#endif
}

// split fp32 -> packed (h,l) f16-pair dword (exact same h/l values as the
// old consumer-side split: h=f16(v), l=f16(v-h))
__device__ inline u32 pack_hl(float v) {
  f16 h = (f16)v;
  f16 l = (f16)(v - (float)h);
  return (u32)__builtin_bit_cast(unsigned short, h) |
         ((u32)__builtin_bit_cast(unsigned short, l) << 16);
}

// ---------------------------------------------------------------------------
// state: 128x3x224x224  conv1 32x3x8x8 s4 -> f1hl (hl-pair) 128x32x55x55
// f1hl -> conv2 64x32x4x4 s2 -> f2hl (hl-pair) 128x64x26x26
// f2hl -> conv3 64x64x3x3 s1 -> x rows fp32 (36864 + 90 history, pad 36960)
// Convs: split-f16 MFMA (hi+lo, 3 MFMAs/product, fp32-quality: absmax 0.0).
// r17: six rounds of evidence -> convs are memory-queue/TLP-bound; time
//   tracks occupancy; intra-wave scheduling changes are neutral-to-negative.
//   Revert to measured-best forms: conv1 = r13 (51.7us), convhl = r13
//   (2 barriers, cooperative LDS staging; r15's A-reg ping-pong was 89us vs
//   ~45). One clean win: pad_w1 ELIMINATED -- fc1 reads w1 directly
//   (align-4 struct loads, explicit zeros at the K boundary; staged values
//   bit-identical to the padded buffer). Saves 18.9MB W + 18.9MB R.
// ---------------------------------------------------------------------------

// Split conv weights into f16 hi/lo pairs; conv3 padded [oc][c][kh][4]
// (kw=3 -> 0). Repack w2 (256x128) -> w2q[k4][j] float4 columns.
__global__ __launch_bounds__(256) void prep_weights_kernel(
    const float* __restrict__ cw1, const float* __restrict__ cw2,
    const float* __restrict__ cw3, const float* __restrict__ w2,
    f16* __restrict__ w1h, f16* __restrict__ w1l,
    f16* __restrict__ w2h, f16* __restrict__ w2l,
    f16* __restrict__ w3h, f16* __restrict__ w3l,
    float* __restrict__ w2q) {
  int i = blockIdx.x * 256 + threadIdx.x;   // grid covers 49152
  if (i < 6144)  { float v = cw1[i]; f16 h = (f16)v; w1h[i] = h; w1l[i] = (f16)(v - (float)h); }
  if (i < 32768) { float v = cw2[i]; f16 h = (f16)v; w2h[i] = h; w2l[i] = (f16)(v - (float)h); }
  if (i < 49152) {
    int oc = i / 768, r = i % 768;
    int c = r / 12, rr = r % 12, kh = rr >> 2, kw = rr & 3;
    float v = (kw < 3) ? cw3[oc * 576 + c * 9 + kh * 3 + kw] : 0.f;
    f16 h = (f16)v; w3h[i] = h; w3l[i] = (f16)(v - (float)h);
  }
  if (i < 32768) {   // w2[j][k] -> w2q[(k4*256 + j)*4 + e]
    int j = i >> 7, k = i & 127;
    w2q[((k >> 2) * 256 + j) * 4 + (k & 3)] = w2[i];
  }
}

// ---------------------------------------------------------------------------
// conv1 (r13): 16x16x32 MFMA layouts (HW-verified): A[m=lane&15][k=quad*8+j],
// B[k=quad*8+j][n=lane&15], C col=lane&15 row=quad*4+reg.
// B slot s (0..511): holds B[k=kt*32+((s>>4)&3)*8+j][npos=(s>>6)*16+(s&15)],
// raw fp32, staged by global_load_lds. Gathers 16B-aligned. Convert to
// split-f16 at fragment read (WOC=1: each slot read once).
// ---------------------------------------------------------------------------
__global__ __launch_bounds__(256) void conv1_kernel(
    const float* __restrict__ in, const f16* __restrict__ wh,
    const f16* __restrict__ wl, const float* __restrict__ bias,
    u32* __restrict__ out) {
  constexpr int K = 192, KCH = 6, OW = 55, OHW = 3025, NPB = 128;
  __shared__ __attribute__((aligned(16))) f16 Ah[2 * 512], Al[2 * 512]; // 4KB
  __shared__ __attribute__((aligned(16))) float Bf[8 * 512];            // 16KB

  const int n = blockIdx.y, pos0 = blockIdx.x * NPB;
  const int t = threadIdx.x;
  const int w = t >> 6, lane = t & 63, quad = lane >> 4, l16 = lane & 15;
  const float* __restrict__ inb = in + (size_t)n * 3 * 224 * 224;

  // staging invariants: rq = filter-row offset within kt (same for both si)
  const int rq = (t >> 4) & 3;
  int base[2];
#pragma unroll
  for (int si = 0; si < 2; ++si) {
    int s = t + si * 256;
    int pos = pos0 + (s >> 6) * 16 + (s & 15);
    if (pos > OHW - 1) pos = OHW - 1;      // clamp (store masked later)
    int oh = pos / OW, ow = pos - oh * OW;
    base[si] = oh * 4 * 224 + ow * 4;
  }
  // A slot (t<128): oc am, k offset ak
  const int am = (t >> 6) * 16 + (t & 15);
  const int ak = ((t >> 4) & 3) * 8;

  int posv[2];
#pragma unroll
  for (int ntl = 0; ntl < 2; ++ntl)
    posv[ntl] = pos0 + (w * 2 + ntl) * 16 + l16;

  f32x4 acc[2][2] = {};

  for (int kt = 0; kt < KCH; ++kt) {
    __syncthreads();
    if (t < 128) {   // stage weights (tiny, plain)
      *(f16x8*)&Ah[t * 8] = *(const f16x8*)&wh[am * K + kt * 32 + ak];
      *(f16x8*)&Al[t * 8] = *(const f16x8*)&wl[am * K + kt * 32 + ak];
    }
    {  // async B staging: 4 global_load_lds per wave
      int r = kt * 4 + rq;
      int c = r >> 3, kh = r & 7;
      int rowoff = c * 50176 + kh * 224;
#pragma unroll
      for (int si = 0; si < 2; ++si)
#pragma unroll
        for (int half = 0; half < 2; ++half)
          GLOAD_LDS16(inb + rowoff + base[si] + half * 4,
                      &Bf[(si * 4 + w) * 512 + half * 256]);
    }
    __syncthreads();   // drains vmcnt: B in LDS, A visible

    f16x8 ah0 = *(const f16x8*)&Ah[0 * 512 + lane * 8];
    f16x8 ah1 = *(const f16x8*)&Ah[1 * 512 + lane * 8];
    f16x8 al0 = *(const f16x8*)&Al[0 * 512 + lane * 8];
    f16x8 al1 = *(const f16x8*)&Al[1 * 512 + lane * 8];
    f16x8 bh[2], bl[2];
#pragma unroll
    for (int ntl = 0; ntl < 2; ++ntl) {
      const float* bp = &Bf[(w * 2 + ntl) * 512 + lane * 4];
      float4 v0 = *(const float4*)bp;
      float4 v1 = *(const float4*)(bp + 256);
      float vv[8] = {v0.x, v0.y, v0.z, v0.w, v1.x, v1.y, v1.z, v1.w};
#pragma unroll
      for (int e = 0; e < 8; ++e) {
        f16 h = (f16)vv[e];
        bh[ntl][e] = h;
        bl[ntl][e] = (f16)(vv[e] - (float)h);
      }
    }
    acc[0][0] = __builtin_amdgcn_mfma_f32_16x16x32_f16(ah0, bh[0], acc[0][0], 0, 0, 0);
    acc[0][0] = __builtin_amdgcn_mfma_f32_16x16x32_f16(ah0, bl[0], acc[0][0], 0, 0, 0);
    acc[0][0] = __builtin_amdgcn_mfma_f32_16x16x32_f16(al0, bh[0], acc[0][0], 0, 0, 0);
    acc[1][0] = __builtin_amdgcn_mfma_f32_16x16x32_f16(ah1, bh[0], acc[1][0], 0, 0, 0);
    acc[1][0] = __builtin_amdgcn_mfma_f32_16x16x32_f16(ah1, bl[0], acc[1][0], 0, 0, 0);
    acc[1][0] = __builtin_amdgcn_mfma_f32_16x16x32_f16(al1, bh[0], acc[1][0], 0, 0, 0);
    acc[0][1] = __builtin_amdgcn_mfma_f32_16x16x32_f16(ah0, bh[1], acc[0][1], 0, 0, 0);
    acc[0][1] = __builtin_amdgcn_mfma_f32_16x16x32_f16(ah0, bl[1], acc[0][1], 0, 0, 0);
    acc[0][1] = __builtin_amdgcn_mfma_f32_16x16x32_f16(al0, bh[1], acc[0][1], 0, 0, 0);
    acc[1][1] = __builtin_amdgcn_mfma_f32_16x16x32_f16(ah1, bh[1], acc[1][1], 0, 0, 0);
    acc[1][1] = __builtin_amdgcn_mfma_f32_16x16x32_f16(ah1, bl[1], acc[1][1], 0, 0, 0);
    acc[1][1] = __builtin_amdgcn_mfma_f32_16x16x32_f16(al1, bh[1], acc[1][1], 0, 0, 0);
  }

#pragma unroll
  for (int mtl = 0; mtl < 2; ++mtl)
#pragma unroll
    for (int ntl = 0; ntl < 2; ++ntl)
#pragma unroll
      for (int r = 0; r < 4; ++r) {
        int oc  = mtl * 16 + quad * 4 + r;
        int pos = posv[ntl];
        if (pos < OHW) {
          float v = acc[mtl][ntl][r] + bias[oc];
          v = v > 0.f ? v : 0.f;
          out[((size_t)n * 32 + oc) * OHW + pos] = pack_hl(v);
        }
      }
}

// ---------------------------------------------------------------------------
// conv2/conv3 (r13 form): input packed (h,l)-pair dwords -> staging is a pure
// dword copy (8 independent loads/thread, no conversion), de-interleave at
// fragment read via v_perm (2 ops per pair). OC=64, NPB=64: MTILES=NTILES=4,
// WOC=2 (waves {0,1} oc-half, {2,3}; wpos = w>>1).
// ---------------------------------------------------------------------------
template<int IC, int KH, int KWP, int KWV, int S, int IH, int IW,
         int OW, int OHW, int OC, int NPB, bool OUT_X>
__global__ __launch_bounds__(256) void convhl_kernel(
    const u32* __restrict__ in, const f16* __restrict__ wh,
    const f16* __restrict__ wl, const float* __restrict__ bias,
    void* __restrict__ outv) {
  constexpr int K = IC * KH * KWP;      // 512 / 768
  constexpr int KCH = K / 32;           // 16 / 24
  __shared__ __attribute__((aligned(16))) f16 Ah[4 * 512], Al[4 * 512]; // 8KB
  __shared__ __attribute__((aligned(16))) u32 Bhl[2][256 * 4];          // 8KB

  const int n = blockIdx.y, pos0 = blockIdx.x * NPB;
  const int t = threadIdx.x;
  const int w = t >> 6, lane = t & 63, quad = lane >> 4, l16 = lane & 15;
  const int woc = w & 1, wpos = w >> 1;
  const u32* __restrict__ inb = in + (size_t)n * IC * IH * IW;

  // B slot s = t: npos = (t>>6)*16 + (t&15); k-rows kt*8 + rq + half
  int pos = pos0 + (t >> 6) * 16 + (t & 15);
  if (pos > OHW - 1) pos = OHW - 1;      // clamp (store masked later)
  int oh = pos / OW, ow = pos - oh * OW;
  const int ohS = oh * S, owS = ow * S;
  const int rq = ((t >> 4) & 3) * 2;
  const int am = (t >> 6) * 16 + (t & 15);
  const int ak = ((t >> 4) & 3) * 8;

  int posv[2];
#pragma unroll
  for (int ntl = 0; ntl < 2; ++ntl)
    posv[ntl] = pos0 + (wpos * 2 + ntl) * 16 + l16;

  f32x4 acc[2][2] = {};

  for (int kt = 0; kt < KCH; ++kt) {
    __syncthreads();
    // stage weights: 8 consecutive k for one oc (all 256 threads)
    *(f16x8*)&Ah[t * 8] = *(const f16x8*)&wh[am * K + kt * 32 + ak];
    *(f16x8*)&Al[t * 8] = *(const f16x8*)&wl[am * K + kt * 32 + ak];
    // stage B: pure hl-dword gather, 4 dwords per half
#pragma unroll
    for (int half = 0; half < 2; ++half) {
      int row = kt * 8 + rq + half;
      int c = row / KH, kh = row - c * KH;
      const u32* p = inb + ((size_t)c * IH + ohS + kh) * IW + owS;
      uint4 d;
      d.x = p[0]; d.y = p[1]; d.z = p[2];
      d.w = (KWV < KWP) ? 0u : p[3];       // conv3: padded kw=3 -> 0
      *(uint4*)&Bhl[half][t * 4] = d;
    }
    __syncthreads();

    f16x8 ah0 = *(const f16x8*)&Ah[(woc * 2 + 0) * 512 + lane * 8];
    f16x8 ah1 = *(const f16x8*)&Ah[(woc * 2 + 1) * 512 + lane * 8];
    f16x8 al0 = *(const f16x8*)&Al[(woc * 2 + 0) * 512 + lane * 8];
    f16x8 al1 = *(const f16x8*)&Al[(woc * 2 + 1) * 512 + lane * 8];
    f16x8 bh[2], bl[2];
#pragma unroll
    for (int ntl = 0; ntl < 2; ++ntl) {
      int sl = ((wpos * 2 + ntl) * 64 + lane) * 4;
      uint4 q0 = *(const uint4*)&Bhl[0][sl];
      uint4 q1 = *(const uint4*)&Bhl[1][sl];
      uint4 hv, lv;
      hv.x = hpair(q0.x, q0.y); lv.x = lpair(q0.x, q0.y);
      hv.y = hpair(q0.z, q0.w); lv.y = lpair(q0.z, q0.w);
      hv.z = hpair(q1.x, q1.y); lv.z = lpair(q1.x, q1.y);
      hv.w = hpair(q1.z, q1.w); lv.w = lpair(q1.z, q1.w);
      bh[ntl] = __builtin_bit_cast(f16x8, hv);
      bl[ntl] = __builtin_bit_cast(f16x8, lv);
    }
    acc[0][0] = __builtin_amdgcn_mfma_f32_16x16x32_f16(ah0, bh[0], acc[0][0], 0, 0, 0);
    acc[0][0] = __builtin_amdgcn_mfma_f32_16x16x32_f16(ah0, bl[0], acc[0][0], 0, 0, 0);
    acc[0][0] = __builtin_amdgcn_mfma_f32_16x16x32_f16(al0, bh[0], acc[0][0], 0, 0, 0);
    acc[1][0] = __builtin_amdgcn_mfma_f32_16x16x32_f16(ah1, bh[0], acc[1][0], 0, 0, 0);
    acc[1][0] = __builtin_amdgcn_mfma_f32_16x16x32_f16(ah1, bl[0], acc[1][0], 0, 0, 0);
    acc[1][0] = __builtin_amdgcn_mfma_f32_16x16x32_f16(al1, bh[0], acc[1][0], 0, 0, 0);
    acc[0][1] = __builtin_amdgcn_mfma_f32_16x16x32_f16(ah0, bh[1], acc[0][1], 0, 0, 0);
    acc[0][1] = __builtin_amdgcn_mfma_f32_16x16x32_f16(ah0, bl[1], acc[0][1], 0, 0, 0);
    acc[0][1] = __builtin_amdgcn_mfma_f32_16x16x32_f16(al0, bh[1], acc[0][1], 0, 0, 0);
    acc[1][1] = __builtin_amdgcn_mfma_f32_16x16x32_f16(ah1, bh[1], acc[1][1], 0, 0, 0);
    acc[1][1] = __builtin_amdgcn_mfma_f32_16x16x32_f16(ah1, bl[1], acc[1][1], 0, 0, 0);
    acc[1][1] = __builtin_amdgcn_mfma_f32_16x16x32_f16(al1, bh[1], acc[1][1], 0, 0, 0);
  }

#pragma unroll
  for (int mtl = 0; mtl < 2; ++mtl)
#pragma unroll
    for (int ntl = 0; ntl < 2; ++ntl)
#pragma unroll
      for (int r = 0; r < 4; ++r) {
        int oc = (woc * 2 + mtl) * 16 + quad * 4 + r;
        int p2 = posv[ntl];
        if (p2 < OHW) {
          float v = acc[mtl][ntl][r] + bias[oc];
          v = v > 0.f ? v : 0.f;
          if constexpr (OUT_X)
            ((float*)outv)[(size_t)n * XS + oc * OHW + p2] = v;
          else
            ((u32*)outv)[((size_t)n * OC + oc) * OHW + p2] = pack_hl(v);
        }
      }
}

// history -> x[:, 36864:36954], zero the pad to 36960
__global__ __launch_bounds__(256) void histpack_kernel(
    const float* __restrict__ h, float* __restrict__ x) {
  int i = blockIdx.x * 256 + threadIdx.x;
  if (i < 128 * 96) {
    int n = i / 96, k = i % 96;
    x[(size_t)n * XS + 36864 + k] = (k < 90) ? h[n * 90 + k] : 0.f;
  }
}

// FC1 (fp32): register-blocked split-K GEMM, 128b x 128j tile per block,
// thread owns 8x8 interleaved sub-tile. P[kt][b][j] deterministic partials.
// r17: reads w1 DIRECTLY (no padded copy): rows stride 36954 floats -> 8B
// alignment on odd rows (F4 struct load), explicit zeros at the K boundary
// (gk=36952 tile) and gk>=36954 -- staged values bit-identical to the old
// zero-padded w1p.
#define FC1_KT 289
__global__ __launch_bounds__(256) void fc1_kernel(
    const float* __restrict__ x, const float* __restrict__ w1,
    float* __restrict__ P) {
  int kt = blockIdx.x;        // 0..288
  int t  = threadIdx.x;
  int bq = t & 15, jq = t >> 4;
  __shared__ float xs[128 * 36];
  __shared__ float wsm[128 * 36];
  float acc[8][8];
#pragma unroll
  for (int bb = 0; bb < 8; ++bb)
#pragma unroll
    for (int jj = 0; jj < 8; ++jj) acc[bb][jj] = 0.f;

  int cs = t & 7;          // float4 column for staging (0..7)
  int rs = t >> 3;         // row base for staging (0..31), 4 passes
#pragma unroll 1
  for (int s = 0; s < 4; ++s) {
    int k0 = kt * 128 + s * 32;
    __syncthreads();
#pragma unroll
    for (int p = 0; p < 4; ++p) {
      int r = rs + p * 32;
      int gk = k0 + cs * 4;
      float4 xv, wv;
      if (gk + 4 <= 36954) {          // fully in-range vector load
        xv = *(const float4*)&x[(size_t)r * XS + gk];
        F4 u = *(const F4*)&w1[(size_t)r * 36954 + gk];
        wv = make_float4(u.x, u.y, u.z, u.w);
      } else if (gk < 36954) {        // boundary tile (gk = 36952)
        xv = *(const float4*)&x[(size_t)r * XS + gk];  // x pad is zeros
        wv.x = w1[(size_t)r * 36954 + gk];
        wv.y = (gk + 1 < 36954) ? w1[(size_t)r * 36954 + gk + 1] : 0.f;
        wv.z = 0.f; wv.w = 0.f;
      } else {
        xv = make_float4(0.f, 0.f, 0.f, 0.f);
        wv = make_float4(0.f, 0.f, 0.f, 0.f);
      }
      *(float4*)&xs[r * 36 + cs * 4] = xv;
      *(float4*)&wsm[r * 36 + cs * 4] = wv;
    }
    __syncthreads();
#pragma unroll 1
    for (int kk = 0; kk < 32; kk += 4) {
      float4 xv[8], wv[8];
#pragma unroll
      for (int i = 0; i < 8; ++i)
        xv[i] = *(const float4*)&xs[(bq + 16 * i) * 36 + kk];
#pragma unroll
      for (int i = 0; i < 8; ++i)
        wv[i] = *(const float4*)&wsm[(jq + 16 * i) * 36 + kk];
#pragma unroll
      for (int bb = 0; bb < 8; ++bb)
#pragma unroll
        for (int jj = 0; jj < 8; ++jj) {
          acc[bb][jj] = fmaf(xv[bb].x, wv[jj].x, acc[bb][jj]);
          acc[bb][jj] = fmaf(xv[bb].y, wv[jj].y, acc[bb][jj]);
          acc[bb][jj] = fmaf(xv[bb].z, wv[jj].z, acc[bb][jj]);
          acc[bb][jj] = fmaf(xv[bb].w, wv[jj].w, acc[bb][jj]);
        }
    }
  }
  float* Pb = P + (size_t)kt * 16384;
#pragma unroll
  for (int bb = 0; bb < 8; ++bb)
#pragma unroll
    for (int jj = 0; jj < 8; ++jj)
      Pb[(bq + 16 * bb) * 128 + jq + 16 * jj] = acc[bb][jj];
}

// Reduce P over kt: h1s[b][j] = sum_kt P[kt][b][j] + b1[j].
// 32 loads in flight per thread (order-preserving: per-accumulator add
// sequences identical to the 4-accumulator loop), 256 blocks x 1 wave.
__global__ __launch_bounds__(64) void reduce_p_kernel(
    const float* __restrict__ P, const float* __restrict__ b1,
    float* __restrict__ h1s) {
  int idx = blockIdx.x * 64 + threadIdx.x;   // 0..16383
  int j = idx & 127;
  float a0 = 0.f, a1 = 0.f, a2 = 0.f, a3 = 0.f;
  int kt = 0;
  for (; kt + 31 < FC1_KT; kt += 32) {
    float v[32];
#pragma unroll
    for (int q = 0; q < 32; ++q)
      v[q] = P[(size_t)(kt + q) * 16384 + idx];
#pragma unroll
    for (int q = 0; q < 32; q += 4) {
      a0 += v[q]; a1 += v[q + 1]; a2 += v[q + 2]; a3 += v[q + 3];
    }
  }
  for (; kt + 3 < FC1_KT; kt += 4) {
    a0 += P[(size_t)(kt + 0) * 16384 + idx];
    a1 += P[(size_t)(kt + 1) * 16384 + idx];
    a2 += P[(size_t)(kt + 2) * 16384 + idx];
    a3 += P[(size_t)(kt + 3) * 16384 + idx];
  }
  for (; kt < FC1_KT; ++kt) a0 += P[(size_t)kt * 16384 + idx];
  h1s[idx] = ((a0 + a1) + (a2 + a3)) + b1[j];
}

// Recurrence: one block per batch row. w2 column in VGPRs (loaded once,
// 32 coalesced dwordx4); spk broadcast via LDS; w3 staged in LDS; layer3
// as 144-thread partials + 9-thread reduce. Critical path ~700 cyc/step.
__global__ __launch_bounds__(256, 1) void recur_kernel(
    const float* __restrict__ h1s,  // [128][128]
    const float4* __restrict__ w2q, // [32][256] float4 cols: w2q[k4*256+j]
    const float* __restrict__ b2,
    const float* __restrict__ w3,   // [9][256]
    const float* __restrict__ b3,
    float* __restrict__ out) {      // [128][9]
  int b = blockIdx.x;
  int t = threadIdx.x;
  __shared__ float spk1s[128];
  __shared__ float spk2s[256];
  __shared__ float w3s[9 * 256];
  __shared__ float part[9][16];
  float4 w2c[32];
#pragma unroll
  for (int k4 = 0; k4 < 32; ++k4) w2c[k4] = w2q[k4 * 256 + t];
  for (int i = t; i < 9 * 256; i += 256) w3s[i] = w3[i];
  float h1 = (t < 128) ? h1s[b * 128 + t] : 0.f;
  float mem1 = 0.f, syn1 = 0.f, mem2 = 0.f, syn2 = 0.f;
  float b2v = b2[t];
  float mem3 = 0.f, syn3 = 0.f, pot = 0.f;
  float b3v = (t < 9) ? b3[t] : 0.f;
  int j3 = t >> 4, p = t & 15;      // layer3 partial owners (t < 144)
  __syncthreads();                  // w3s ready

  for (int step = 0; step < 10; ++step) {
    if (t < 128) {
      syn1 = ALPHA * syn1 + h1;
      mem1 = BETA * mem1 + syn1;
      float s = (mem1 > 1.0f) ? 1.0f : 0.0f;
      mem1 -= s;
      spk1s[t] = s;
    }
    __syncthreads();
    float h2 = b2v;
#pragma unroll
    for (int k4 = 0; k4 < 32; ++k4) {
      float4 s = *(const float4*)&spk1s[k4 * 4];   // broadcast read
      h2 = fmaf(s.x, w2c[k4].x, h2);
      h2 = fmaf(s.y, w2c[k4].y, h2);
      h2 = fmaf(s.z, w2c[k4].z, h2);
      h2 = fmaf(s.w, w2c[k4].w, h2);
    }
    syn2 = ALPHA * syn2 + h2;
    mem2 = BETA * mem2 + syn2;
    float s2 = (mem2 > 1.0f) ? 1.0f : 0.0f;
    mem2 -= s2;
    spk2s[t] = s2;
    __syncthreads();
    if (t < 144) {
      float a = 0.f;
      const float* wr = &w3s[j3 * 256 + p * 16];
      const float* sp = &spk2s[p * 16];
#pragma unroll
      for (int e = 0; e < 16; ++e) a = fmaf(sp[e], wr[e], a);
      part[j3][p] = a;
    }
    __syncthreads();
    if (t < 9) {
      float a = b3v;
#pragma unroll
      for (int p2 = 0; p2 < 16; ++p2) a += part[t][p2];
      syn3 = ALPHA * syn3 + a;
      mem3 = BETA * mem3 + syn3;
      pot += mem3;
    }
  }
  if (t < 9) out[b * 9 + t] = pot * 0.1f;
}

extern "C" void kernel_launch(void* const* d_in, const int* in_sizes, int n_in,
                              void* d_out, int out_size, void* d_ws, size_t ws_size,
                              hipStream_t stream) {
  const float* state   = (const float*)d_in[0];
  const float* history = (const float*)d_in[1];
  const float* cw1 = (const float*)d_in[2];
  const float* cb1 = (const float*)d_in[3];
  const float* cw2 = (const float*)d_in[4];
  const float* cb2 = (const float*)d_in[5];
  const float* cw3 = (const float*)d_in[6];
  const float* cb3 = (const float*)d_in[7];
  const float* w1  = (const float*)d_in[8];
  const float* b1  = (const float*)d_in[9];
  const float* w2  = (const float*)d_in[10];
  const float* b2  = (const float*)d_in[11];
  const float* w3  = (const float*)d_in[12];
  const float* b3  = (const float*)d_in[13];
  float* out = (float*)d_out;
  char* ws = (char*)d_ws;

  // workspace (bytes), time-multiplexed:
  //  f1hl  [0, 49,561,600)              conv1 -> conv2  (hl-pair dwords)
  //    xb  [0, 18,923,520)              conv3 -> fc1    (f1hl dead)
  //  f2hl  [49,561,600, 71,712,768)     conv2 -> conv3  (hl-pair dwords)
  //    P   [49,561,600, 68,501,504)     fc1 -> reduce   (f2hl dead)
  //  small weights [71,712,768, 72,261,632)
  u32*   f1hl = (u32*)(ws + 0);
  float* xb   = (float*)(ws + 0);
  u32*   f2hl = (u32*)(ws + 49561600);
  float* P    = (float*)(ws + 49561600);
  f16* wf1h = (f16*)(ws + 71712768);   // 12,288
  f16* wf1l = (f16*)(ws + 71725056);   // 12,288
  f16* wf2h = (f16*)(ws + 71737344);   // 65,536
  f16* wf2l = (f16*)(ws + 71802880);   // 65,536
  f16* wf3h = (f16*)(ws + 71868416);   // 98,304 (padded K=768)
  f16* wf3l = (f16*)(ws + 71966720);   // 98,304
  float* w2q = (float*)(ws + 72065024);  // 131,072
  float* h1s = (float*)(ws + 72196096);  // 65,536 (end 72,261,632)

  prep_weights_kernel<<<192, 256, 0, stream>>>(cw1, cw2, cw3, w2,
                                               wf1h, wf1l, wf2h, wf2l,
                                               wf3h, wf3l, w2q);
  // conv1: 224x224 -> 55x55(3025), OC=32, NPB=128, async-LDS staged (r13)
  conv1_kernel<<<dim3(24, 128), 256, 0, stream>>>(state, wf1h, wf1l, cb1, f1hl);
  // conv2: IC=32,KH=4,KWP=4,KWV=4,S=2, 55x55 -> 26x26(676), OC=64, NPB=64
  convhl_kernel<32, 4, 4, 4, 2, 55, 55, 26, 676, 64, 64, false>
      <<<dim3(11, 128), 256, 0, stream>>>(f1hl, wf2h, wf2l, cb2, (void*)f2hl);
  // conv3: IC=64,KH=3,KWP=4,KWV=3,S=1, 26x26 -> 24x24(576), OC=64, NPB=64 -> x
  convhl_kernel<64, 3, 4, 3, 1, 26, 26, 24, 576, 64, 64, true>
      <<<dim3(9, 128), 256, 0, stream>>>(f2hl, wf3h, wf3l, cb3, (void*)xb);
  histpack_kernel<<<48, 256, 0, stream>>>(history, xb);
  fc1_kernel<<<FC1_KT, 256, 0, stream>>>(xb, w1, P);
  reduce_p_kernel<<<256, 64, 0, stream>>>(P, b1, h1s);
  recur_kernel<<<128, 256, 0, stream>>>(h1s, (const float4*)w2q, b2, w3, b3, out);
}

// Round 9
// 321.630 us; speedup vs baseline: 1.2372x; 1.0544x over previous
//
#include <hip/hip_runtime.h>

#define ALPHA 0.9f
#define BETA  0.8f
#define XS 36960   // padded row stride for x

typedef _Float16 f16;
typedef _Float16 f16x8 __attribute__((ext_vector_type(8)));
typedef float f32x4 __attribute__((ext_vector_type(4)));
typedef unsigned int u32;

// 16B load at only-4B-known alignment (w1 rows stride 36954 floats -> odd
// rows are 8B-aligned). Backend emits unaligned wide loads; same bytes.
struct F4 { float x, y, z, w; };   // alignof = 4

// async global->LDS DMA, 16B per lane: per-lane global src, wave-uniform LDS
// base + lane*16 dest (m97 pattern).
#define GLOAD_LDS16(gsrc, ldst)                                        \
  __builtin_amdgcn_global_load_lds(                                    \
      (const __attribute__((address_space(1))) void*)(gsrc),           \
      (__attribute__((address_space(3))) void*)(ldst), 16, 0, 0)

// de-interleave (h,l)-pair dwords: hpair = h1<<16|h0, lpair = l1<<16|l0
__device__ inline u32 hpair(u32 d0, u32 d1) {
#if __has_builtin(__builtin_amdgcn_perm)
  return __builtin_amdgcn_perm(d1, d0, 0x05040100u);
#else
  return (d0 & 0xffffu) | (d1 << 16);
#endif
}
__device__ inline u32 lpair(u32 d0, u32 d1) {
#if __has_builtin(__builtin_amdgcn_perm)
  return __builtin_amdgcn_perm(d1, d0, 0x07060302u);
#else
  return (d0 >> 16) | (d1 & 0xffff0000u);
#endif
}

// split fp32 -> packed (h,l) f16-pair dword (exact same h/l values as the
// old consumer-side split: h=f16(v), l=f16(v-h))
__device__ inline u32 pack_hl(float v) {
  f16 h = (f16)v;
  f16 l = (f16)(v - (float)h);
  return (u32)__builtin_bit_cast(unsigned short, h) |
         ((u32)__builtin_bit_cast(unsigned short, l) << 16);
}

// ---------------------------------------------------------------------------
// state: 128x3x224x224  conv1 32x3x8x8 s4 -> f1hl (hl-pair) 128x32x55x55
// f1hl -> conv2 64x32x4x4 s2 -> f2hl (hl-pair) 128x64x26x26
// f2hl -> conv3 64x64x3x3 s1 -> x rows fp32 (36864 + 90 history, pad 36960)
// Convs: split-f16 MFMA (hi+lo, 3 MFMAs/product, fp32-quality: absmax 0.0).
// r18: fc1 was 51.9us at 8.7% occupancy (289 blocks = 1.13/CU, pure
//   latency-bound: 775 GB/s, VALUBusy 18%). Split the BATCH dim x4 (32b x
//   128j per block, grid 1156, LDS 23KB) -- K-chunking untouched, so each
//   (b,j,kt) partial keeps its unbroken kk FMA chain: P bitwise identical,
//   h1 bitwise identical, spikes can't flip. w1 re-reads are L3-resident.
//   Convs/reduce/recur = r17 verbatim (339.1us best).
// ---------------------------------------------------------------------------

// Split conv weights into f16 hi/lo pairs; conv3 padded [oc][c][kh][4]
// (kw=3 -> 0). Repack w2 (256x128) -> w2q[k4][j] float4 columns.
__global__ __launch_bounds__(256) void prep_weights_kernel(
    const float* __restrict__ cw1, const float* __restrict__ cw2,
    const float* __restrict__ cw3, const float* __restrict__ w2,
    f16* __restrict__ w1h, f16* __restrict__ w1l,
    f16* __restrict__ w2h, f16* __restrict__ w2l,
    f16* __restrict__ w3h, f16* __restrict__ w3l,
    float* __restrict__ w2q) {
  int i = blockIdx.x * 256 + threadIdx.x;   // grid covers 49152
  if (i < 6144)  { float v = cw1[i]; f16 h = (f16)v; w1h[i] = h; w1l[i] = (f16)(v - (float)h); }
  if (i < 32768) { float v = cw2[i]; f16 h = (f16)v; w2h[i] = h; w2l[i] = (f16)(v - (float)h); }
  if (i < 49152) {
    int oc = i / 768, r = i % 768;
    int c = r / 12, rr = r % 12, kh = rr >> 2, kw = rr & 3;
    float v = (kw < 3) ? cw3[oc * 576 + c * 9 + kh * 3 + kw] : 0.f;
    f16 h = (f16)v; w3h[i] = h; w3l[i] = (f16)(v - (float)h);
  }
  if (i < 32768) {   // w2[j][k] -> w2q[(k4*256 + j)*4 + e]
    int j = i >> 7, k = i & 127;
    w2q[((k >> 2) * 256 + j) * 4 + (k & 3)] = w2[i];
  }
}

// ---------------------------------------------------------------------------
// conv1 (r13): 16x16x32 MFMA layouts (HW-verified): A[m=lane&15][k=quad*8+j],
// B[k=quad*8+j][n=lane&15], C col=lane&15 row=quad*4+reg.
// B slot s (0..511): holds B[k=kt*32+((s>>4)&3)*8+j][npos=(s>>6)*16+(s&15)],
// raw fp32, staged by global_load_lds. Gathers 16B-aligned. Convert to
// split-f16 at fragment read (WOC=1: each slot read once).
// ---------------------------------------------------------------------------
__global__ __launch_bounds__(256) void conv1_kernel(
    const float* __restrict__ in, const f16* __restrict__ wh,
    const f16* __restrict__ wl, const float* __restrict__ bias,
    u32* __restrict__ out) {
  constexpr int K = 192, KCH = 6, OW = 55, OHW = 3025, NPB = 128;
  __shared__ __attribute__((aligned(16))) f16 Ah[2 * 512], Al[2 * 512]; // 4KB
  __shared__ __attribute__((aligned(16))) float Bf[8 * 512];            // 16KB

  const int n = blockIdx.y, pos0 = blockIdx.x * NPB;
  const int t = threadIdx.x;
  const int w = t >> 6, lane = t & 63, quad = lane >> 4, l16 = lane & 15;
  const float* __restrict__ inb = in + (size_t)n * 3 * 224 * 224;

  // staging invariants: rq = filter-row offset within kt (same for both si)
  const int rq = (t >> 4) & 3;
  int base[2];
#pragma unroll
  for (int si = 0; si < 2; ++si) {
    int s = t + si * 256;
    int pos = pos0 + (s >> 6) * 16 + (s & 15);
    if (pos > OHW - 1) pos = OHW - 1;      // clamp (store masked later)
    int oh = pos / OW, ow = pos - oh * OW;
    base[si] = oh * 4 * 224 + ow * 4;
  }
  // A slot (t<128): oc am, k offset ak
  const int am = (t >> 6) * 16 + (t & 15);
  const int ak = ((t >> 4) & 3) * 8;

  int posv[2];
#pragma unroll
  for (int ntl = 0; ntl < 2; ++ntl)
    posv[ntl] = pos0 + (w * 2 + ntl) * 16 + l16;

  f32x4 acc[2][2] = {};

  for (int kt = 0; kt < KCH; ++kt) {
    __syncthreads();
    if (t < 128) {   // stage weights (tiny, plain)
      *(f16x8*)&Ah[t * 8] = *(const f16x8*)&wh[am * K + kt * 32 + ak];
      *(f16x8*)&Al[t * 8] = *(const f16x8*)&wl[am * K + kt * 32 + ak];
    }
    {  // async B staging: 4 global_load_lds per wave
      int r = kt * 4 + rq;
      int c = r >> 3, kh = r & 7;
      int rowoff = c * 50176 + kh * 224;
#pragma unroll
      for (int si = 0; si < 2; ++si)
#pragma unroll
        for (int half = 0; half < 2; ++half)
          GLOAD_LDS16(inb + rowoff + base[si] + half * 4,
                      &Bf[(si * 4 + w) * 512 + half * 256]);
    }
    __syncthreads();   // drains vmcnt: B in LDS, A visible

    f16x8 ah0 = *(const f16x8*)&Ah[0 * 512 + lane * 8];
    f16x8 ah1 = *(const f16x8*)&Ah[1 * 512 + lane * 8];
    f16x8 al0 = *(const f16x8*)&Al[0 * 512 + lane * 8];
    f16x8 al1 = *(const f16x8*)&Al[1 * 512 + lane * 8];
    f16x8 bh[2], bl[2];
#pragma unroll
    for (int ntl = 0; ntl < 2; ++ntl) {
      const float* bp = &Bf[(w * 2 + ntl) * 512 + lane * 4];
      float4 v0 = *(const float4*)bp;
      float4 v1 = *(const float4*)(bp + 256);
      float vv[8] = {v0.x, v0.y, v0.z, v0.w, v1.x, v1.y, v1.z, v1.w};
#pragma unroll
      for (int e = 0; e < 8; ++e) {
        f16 h = (f16)vv[e];
        bh[ntl][e] = h;
        bl[ntl][e] = (f16)(vv[e] - (float)h);
      }
    }
    acc[0][0] = __builtin_amdgcn_mfma_f32_16x16x32_f16(ah0, bh[0], acc[0][0], 0, 0, 0);
    acc[0][0] = __builtin_amdgcn_mfma_f32_16x16x32_f16(ah0, bl[0], acc[0][0], 0, 0, 0);
    acc[0][0] = __builtin_amdgcn_mfma_f32_16x16x32_f16(al0, bh[0], acc[0][0], 0, 0, 0);
    acc[1][0] = __builtin_amdgcn_mfma_f32_16x16x32_f16(ah1, bh[0], acc[1][0], 0, 0, 0);
    acc[1][0] = __builtin_amdgcn_mfma_f32_16x16x32_f16(ah1, bl[0], acc[1][0], 0, 0, 0);
    acc[1][0] = __builtin_amdgcn_mfma_f32_16x16x32_f16(al1, bh[0], acc[1][0], 0, 0, 0);
    acc[0][1] = __builtin_amdgcn_mfma_f32_16x16x32_f16(ah0, bh[1], acc[0][1], 0, 0, 0);
    acc[0][1] = __builtin_amdgcn_mfma_f32_16x16x32_f16(ah0, bl[1], acc[0][1], 0, 0, 0);
    acc[0][1] = __builtin_amdgcn_mfma_f32_16x16x32_f16(al0, bh[1], acc[0][1], 0, 0, 0);
    acc[1][1] = __builtin_amdgcn_mfma_f32_16x16x32_f16(ah1, bh[1], acc[1][1], 0, 0, 0);
    acc[1][1] = __builtin_amdgcn_mfma_f32_16x16x32_f16(ah1, bl[1], acc[1][1], 0, 0, 0);
    acc[1][1] = __builtin_amdgcn_mfma_f32_16x16x32_f16(al1, bh[1], acc[1][1], 0, 0, 0);
  }

#pragma unroll
  for (int mtl = 0; mtl < 2; ++mtl)
#pragma unroll
    for (int ntl = 0; ntl < 2; ++ntl)
#pragma unroll
      for (int r = 0; r < 4; ++r) {
        int oc  = mtl * 16 + quad * 4 + r;
        int pos = posv[ntl];
        if (pos < OHW) {
          float v = acc[mtl][ntl][r] + bias[oc];
          v = v > 0.f ? v : 0.f;
          out[((size_t)n * 32 + oc) * OHW + pos] = pack_hl(v);
        }
      }
}

// ---------------------------------------------------------------------------
// conv2/conv3 (r13 form): input packed (h,l)-pair dwords -> staging is a pure
// dword copy (8 independent loads/thread, no conversion), de-interleave at
// fragment read via v_perm (2 ops per pair). OC=64, NPB=64: MTILES=NTILES=4,
// WOC=2 (waves {0,1} oc-half, {2,3}; wpos = w>>1).
// ---------------------------------------------------------------------------
template<int IC, int KH, int KWP, int KWV, int S, int IH, int IW,
         int OW, int OHW, int OC, int NPB, bool OUT_X>
__global__ __launch_bounds__(256) void convhl_kernel(
    const u32* __restrict__ in, const f16* __restrict__ wh,
    const f16* __restrict__ wl, const float* __restrict__ bias,
    void* __restrict__ outv) {
  constexpr int K = IC * KH * KWP;      // 512 / 768
  constexpr int KCH = K / 32;           // 16 / 24
  __shared__ __attribute__((aligned(16))) f16 Ah[4 * 512], Al[4 * 512]; // 8KB
  __shared__ __attribute__((aligned(16))) u32 Bhl[2][256 * 4];          // 8KB

  const int n = blockIdx.y, pos0 = blockIdx.x * NPB;
  const int t = threadIdx.x;
  const int w = t >> 6, lane = t & 63, quad = lane >> 4, l16 = lane & 15;
  const int woc = w & 1, wpos = w >> 1;
  const u32* __restrict__ inb = in + (size_t)n * IC * IH * IW;

  // B slot s = t: npos = (t>>6)*16 + (t&15); k-rows kt*8 + rq + half
  int pos = pos0 + (t >> 6) * 16 + (t & 15);
  if (pos > OHW - 1) pos = OHW - 1;      // clamp (store masked later)
  int oh = pos / OW, ow = pos - oh * OW;
  const int ohS = oh * S, owS = ow * S;
  const int rq = ((t >> 4) & 3) * 2;
  const int am = (t >> 6) * 16 + (t & 15);
  const int ak = ((t >> 4) & 3) * 8;

  int posv[2];
#pragma unroll
  for (int ntl = 0; ntl < 2; ++ntl)
    posv[ntl] = pos0 + (wpos * 2 + ntl) * 16 + l16;

  f32x4 acc[2][2] = {};

  for (int kt = 0; kt < KCH; ++kt) {
    __syncthreads();
    // stage weights: 8 consecutive k for one oc (all 256 threads)
    *(f16x8*)&Ah[t * 8] = *(const f16x8*)&wh[am * K + kt * 32 + ak];
    *(f16x8*)&Al[t * 8] = *(const f16x8*)&wl[am * K + kt * 32 + ak];
    // stage B: pure hl-dword gather, 4 dwords per half
#pragma unroll
    for (int half = 0; half < 2; ++half) {
      int row = kt * 8 + rq + half;
      int c = row / KH, kh = row - c * KH;
      const u32* p = inb + ((size_t)c * IH + ohS + kh) * IW + owS;
      uint4 d;
      d.x = p[0]; d.y = p[1]; d.z = p[2];
      d.w = (KWV < KWP) ? 0u : p[3];       // conv3: padded kw=3 -> 0
      *(uint4*)&Bhl[half][t * 4] = d;
    }
    __syncthreads();

    f16x8 ah0 = *(const f16x8*)&Ah[(woc * 2 + 0) * 512 + lane * 8];
    f16x8 ah1 = *(const f16x8*)&Ah[(woc * 2 + 1) * 512 + lane * 8];
    f16x8 al0 = *(const f16x8*)&Al[(woc * 2 + 0) * 512 + lane * 8];
    f16x8 al1 = *(const f16x8*)&Al[(woc * 2 + 1) * 512 + lane * 8];
    f16x8 bh[2], bl[2];
#pragma unroll
    for (int ntl = 0; ntl < 2; ++ntl) {
      int sl = ((wpos * 2 + ntl) * 64 + lane) * 4;
      uint4 q0 = *(const uint4*)&Bhl[0][sl];
      uint4 q1 = *(const uint4*)&Bhl[1][sl];
      uint4 hv, lv;
      hv.x = hpair(q0.x, q0.y); lv.x = lpair(q0.x, q0.y);
      hv.y = hpair(q0.z, q0.w); lv.y = lpair(q0.z, q0.w);
      hv.z = hpair(q1.x, q1.y); lv.z = lpair(q1.x, q1.y);
      hv.w = hpair(q1.z, q1.w); lv.w = lpair(q1.z, q1.w);
      bh[ntl] = __builtin_bit_cast(f16x8, hv);
      bl[ntl] = __builtin_bit_cast(f16x8, lv);
    }
    acc[0][0] = __builtin_amdgcn_mfma_f32_16x16x32_f16(ah0, bh[0], acc[0][0], 0, 0, 0);
    acc[0][0] = __builtin_amdgcn_mfma_f32_16x16x32_f16(ah0, bl[0], acc[0][0], 0, 0, 0);
    acc[0][0] = __builtin_amdgcn_mfma_f32_16x16x32_f16(al0, bh[0], acc[0][0], 0, 0, 0);
    acc[1][0] = __builtin_amdgcn_mfma_f32_16x16x32_f16(ah1, bh[0], acc[1][0], 0, 0, 0);
    acc[1][0] = __builtin_amdgcn_mfma_f32_16x16x32_f16(ah1, bl[0], acc[1][0], 0, 0, 0);
    acc[1][0] = __builtin_amdgcn_mfma_f32_16x16x32_f16(al1, bh[0], acc[1][0], 0, 0, 0);
    acc[0][1] = __builtin_amdgcn_mfma_f32_16x16x32_f16(ah0, bh[1], acc[0][1], 0, 0, 0);
    acc[0][1] = __builtin_amdgcn_mfma_f32_16x16x32_f16(ah0, bl[1], acc[0][1], 0, 0, 0);
    acc[0][1] = __builtin_amdgcn_mfma_f32_16x16x32_f16(al0, bh[1], acc[0][1], 0, 0, 0);
    acc[1][1] = __builtin_amdgcn_mfma_f32_16x16x32_f16(ah1, bh[1], acc[1][1], 0, 0, 0);
    acc[1][1] = __builtin_amdgcn_mfma_f32_16x16x32_f16(ah1, bl[1], acc[1][1], 0, 0, 0);
    acc[1][1] = __builtin_amdgcn_mfma_f32_16x16x32_f16(al1, bh[1], acc[1][1], 0, 0, 0);
  }

#pragma unroll
  for (int mtl = 0; mtl < 2; ++mtl)
#pragma unroll
    for (int ntl = 0; ntl < 2; ++ntl)
#pragma unroll
      for (int r = 0; r < 4; ++r) {
        int oc = (woc * 2 + mtl) * 16 + quad * 4 + r;
        int p2 = posv[ntl];
        if (p2 < OHW) {
          float v = acc[mtl][ntl][r] + bias[oc];
          v = v > 0.f ? v : 0.f;
          if constexpr (OUT_X)
            ((float*)outv)[(size_t)n * XS + oc * OHW + p2] = v;
          else
            ((u32*)outv)[((size_t)n * OC + oc) * OHW + p2] = pack_hl(v);
        }
      }
}

// history -> x[:, 36864:36954], zero the pad to 36960
__global__ __launch_bounds__(256) void histpack_kernel(
    const float* __restrict__ h, float* __restrict__ x) {
  int i = blockIdx.x * 256 + threadIdx.x;
  if (i < 128 * 96) {
    int n = i / 96, k = i % 96;
    x[(size_t)n * XS + 36864 + k] = (k < 90) ? h[n * 90 + k] : 0.f;
  }
}

// FC1 (fp32): register-blocked split-K GEMM. r18: 32b x 128j tile per block
// (batch split x4, grid FC1_KT*4) for occupancy; K-chunking UNchanged so
// every (b,j,kt) partial keeps its unbroken kk FMA chain -> P bitwise
// identical to the 128b-tile version. Reads w1 directly (align-4 loads,
// explicit zeros at the K boundary).
#define FC1_KT 289
__global__ __launch_bounds__(256) void fc1_kernel(
    const float* __restrict__ x, const float* __restrict__ w1,
    float* __restrict__ P) {
  int kt = blockIdx.x >> 2;       // 0..288
  int b4 = blockIdx.x & 3;        // batch quarter (32 rows)
  int t  = threadIdx.x;
  int bq = t & 3, jq = t >> 2;    // bq 0..3, jq 0..63
  __shared__ float xs[32 * 36];
  __shared__ float wsm[128 * 36];
  float acc[8][2];
#pragma unroll
  for (int bb = 0; bb < 8; ++bb)
#pragma unroll
    for (int jj = 0; jj < 2; ++jj) acc[bb][jj] = 0.f;

  int cs = t & 7;          // float4 column for staging (0..7)
  int rs = t >> 3;         // row for staging (0..31)
#pragma unroll 1
  for (int s = 0; s < 4; ++s) {
    int k0 = kt * 128 + s * 32;
    int gk = k0 + cs * 4;
    __syncthreads();
    {  // stage x: 32 rows (global b4*32 + rs), one float4/thread
      float4 xv;
      if (gk < 36954)      // x pad [36954,36960) is zeros -> float4 safe
        xv = *(const float4*)&x[(size_t)(b4 * 32 + rs) * XS + gk];
      else
        xv = make_float4(0.f, 0.f, 0.f, 0.f);
      *(float4*)&xs[rs * 36 + cs * 4] = xv;
    }
#pragma unroll
    for (int p = 0; p < 4; ++p) {  // stage w1: 128 rows, 4 passes
      int r = rs + p * 32;
      float4 wv;
      if (gk + 4 <= 36954) {
        F4 u = *(const F4*)&w1[(size_t)r * 36954 + gk];
        wv = make_float4(u.x, u.y, u.z, u.w);
      } else if (gk < 36954) {     // boundary tile (gk = 36952)
        wv.x = w1[(size_t)r * 36954 + gk];
        wv.y = (gk + 1 < 36954) ? w1[(size_t)r * 36954 + gk + 1] : 0.f;
        wv.z = 0.f; wv.w = 0.f;
      } else {
        wv = make_float4(0.f, 0.f, 0.f, 0.f);
      }
      *(float4*)&wsm[r * 36 + cs * 4] = wv;
    }
    __syncthreads();
#pragma unroll 1
    for (int kk = 0; kk < 32; kk += 4) {
      float4 xv[8], wv[2];
#pragma unroll
      for (int i = 0; i < 8; ++i)
        xv[i] = *(const float4*)&xs[(bq + 4 * i) * 36 + kk];
#pragma unroll
      for (int i = 0; i < 2; ++i)
        wv[i] = *(const float4*)&wsm[(jq + 64 * i) * 36 + kk];
#pragma unroll
      for (int bb = 0; bb < 8; ++bb)
#pragma unroll
        for (int jj = 0; jj < 2; ++jj) {
          acc[bb][jj] = fmaf(xv[bb].x, wv[jj].x, acc[bb][jj]);
          acc[bb][jj] = fmaf(xv[bb].y, wv[jj].y, acc[bb][jj]);
          acc[bb][jj] = fmaf(xv[bb].z, wv[jj].z, acc[bb][jj]);
          acc[bb][jj] = fmaf(xv[bb].w, wv[jj].w, acc[bb][jj]);
        }
    }
  }
  float* Pb = P + (size_t)kt * 16384;
#pragma unroll
  for (int bb = 0; bb < 8; ++bb)
#pragma unroll
    for (int jj = 0; jj < 2; ++jj)
      Pb[(b4 * 32 + bq + 4 * bb) * 128 + jq + 64 * jj] = acc[bb][jj];
}

// Reduce P over kt: h1s[b][j] = sum_kt P[kt][b][j] + b1[j].
// 32 loads in flight per thread (order-preserving: per-accumulator add
// sequences identical to the 4-accumulator loop), 256 blocks x 1 wave.
__global__ __launch_bounds__(64) void reduce_p_kernel(
    const float* __restrict__ P, const float* __restrict__ b1,
    float* __restrict__ h1s) {
  int idx = blockIdx.x * 64 + threadIdx.x;   // 0..16383
  int j = idx & 127;
  float a0 = 0.f, a1 = 0.f, a2 = 0.f, a3 = 0.f;
  int kt = 0;
  for (; kt + 31 < FC1_KT; kt += 32) {
    float v[32];
#pragma unroll
    for (int q = 0; q < 32; ++q)
      v[q] = P[(size_t)(kt + q) * 16384 + idx];
#pragma unroll
    for (int q = 0; q < 32; q += 4) {
      a0 += v[q]; a1 += v[q + 1]; a2 += v[q + 2]; a3 += v[q + 3];
    }
  }
  for (; kt + 3 < FC1_KT; kt += 4) {
    a0 += P[(size_t)(kt + 0) * 16384 + idx];
    a1 += P[(size_t)(kt + 1) * 16384 + idx];
    a2 += P[(size_t)(kt + 2) * 16384 + idx];
    a3 += P[(size_t)(kt + 3) * 16384 + idx];
  }
  for (; kt < FC1_KT; ++kt) a0 += P[(size_t)kt * 16384 + idx];
  h1s[idx] = ((a0 + a1) + (a2 + a3)) + b1[j];
}

// Recurrence: one block per batch row. w2 column in VGPRs (loaded once,
// 32 coalesced dwordx4); spk broadcast via LDS; w3 staged in LDS; layer3
// as 144-thread partials + 9-thread reduce. Critical path ~700 cyc/step.
__global__ __launch_bounds__(256, 1) void recur_kernel(
    const float* __restrict__ h1s,  // [128][128]
    const float4* __restrict__ w2q, // [32][256] float4 cols: w2q[k4*256+j]
    const float* __restrict__ b2,
    const float* __restrict__ w3,   // [9][256]
    const float* __restrict__ b3,
    float* __restrict__ out) {      // [128][9]
  int b = blockIdx.x;
  int t = threadIdx.x;
  __shared__ float spk1s[128];
  __shared__ float spk2s[256];
  __shared__ float w3s[9 * 256];
  __shared__ float part[9][16];
  float4 w2c[32];
#pragma unroll
  for (int k4 = 0; k4 < 32; ++k4) w2c[k4] = w2q[k4 * 256 + t];
  for (int i = t; i < 9 * 256; i += 256) w3s[i] = w3[i];
  float h1 = (t < 128) ? h1s[b * 128 + t] : 0.f;
  float mem1 = 0.f, syn1 = 0.f, mem2 = 0.f, syn2 = 0.f;
  float b2v = b2[t];
  float mem3 = 0.f, syn3 = 0.f, pot = 0.f;
  float b3v = (t < 9) ? b3[t] : 0.f;
  int j3 = t >> 4, p = t & 15;      // layer3 partial owners (t < 144)
  __syncthreads();                  // w3s ready

  for (int step = 0; step < 10; ++step) {
    if (t < 128) {
      syn1 = ALPHA * syn1 + h1;
      mem1 = BETA * mem1 + syn1;
      float s = (mem1 > 1.0f) ? 1.0f : 0.0f;
      mem1 -= s;
      spk1s[t] = s;
    }
    __syncthreads();
    float h2 = b2v;
#pragma unroll
    for (int k4 = 0; k4 < 32; ++k4) {
      float4 s = *(const float4*)&spk1s[k4 * 4];   // broadcast read
      h2 = fmaf(s.x, w2c[k4].x, h2);
      h2 = fmaf(s.y, w2c[k4].y, h2);
      h2 = fmaf(s.z, w2c[k4].z, h2);
      h2 = fmaf(s.w, w2c[k4].w, h2);
    }
    syn2 = ALPHA * syn2 + h2;
    mem2 = BETA * mem2 + syn2;
    float s2 = (mem2 > 1.0f) ? 1.0f : 0.0f;
    mem2 -= s2;
    spk2s[t] = s2;
    __syncthreads();
    if (t < 144) {
      float a = 0.f;
      const float* wr = &w3s[j3 * 256 + p * 16];
      const float* sp = &spk2s[p * 16];
#pragma unroll
      for (int e = 0; e < 16; ++e) a = fmaf(sp[e], wr[e], a);
      part[j3][p] = a;
    }
    __syncthreads();
    if (t < 9) {
      float a = b3v;
#pragma unroll
      for (int p2 = 0; p2 < 16; ++p2) a += part[t][p2];
      syn3 = ALPHA * syn3 + a;
      mem3 = BETA * mem3 + syn3;
      pot += mem3;
    }
  }
  if (t < 9) out[b * 9 + t] = pot * 0.1f;
}

extern "C" void kernel_launch(void* const* d_in, const int* in_sizes, int n_in,
                              void* d_out, int out_size, void* d_ws, size_t ws_size,
                              hipStream_t stream) {
  const float* state   = (const float*)d_in[0];
  const float* history = (const float*)d_in[1];
  const float* cw1 = (const float*)d_in[2];
  const float* cb1 = (const float*)d_in[3];
  const float* cw2 = (const float*)d_in[4];
  const float* cb2 = (const float*)d_in[5];
  const float* cw3 = (const float*)d_in[6];
  const float* cb3 = (const float*)d_in[7];
  const float* w1  = (const float*)d_in[8];
  const float* b1  = (const float*)d_in[9];
  const float* w2  = (const float*)d_in[10];
  const float* b2  = (const float*)d_in[11];
  const float* w3  = (const float*)d_in[12];
  const float* b3  = (const float*)d_in[13];
  float* out = (float*)d_out;
  char* ws = (char*)d_ws;

  // workspace (bytes), time-multiplexed:
  //  f1hl  [0, 49,561,600)              conv1 -> conv2  (hl-pair dwords)
  //    xb  [0, 18,923,520)              conv3 -> fc1    (f1hl dead)
  //  f2hl  [49,561,600, 71,712,768)     conv2 -> conv3  (hl-pair dwords)
  //    P   [49,561,600, 68,501,504)     fc1 -> reduce   (f2hl dead)
  //  small weights [71,712,768, 72,261,632)
  u32*   f1hl = (u32*)(ws + 0);
  float* xb   = (float*)(ws + 0);
  u32*   f2hl = (u32*)(ws + 49561600);
  float* P    = (float*)(ws + 49561600);
  f16* wf1h = (f16*)(ws + 71712768);   // 12,288
  f16* wf1l = (f16*)(ws + 71725056);   // 12,288
  f16* wf2h = (f16*)(ws + 71737344);   // 65,536
  f16* wf2l = (f16*)(ws + 71802880);   // 65,536
  f16* wf3h = (f16*)(ws + 71868416);   // 98,304 (padded K=768)
  f16* wf3l = (f16*)(ws + 71966720);   // 98,304
  float* w2q = (float*)(ws + 72065024);  // 131,072
  float* h1s = (float*)(ws + 72196096);  // 65,536 (end 72,261,632)

  prep_weights_kernel<<<192, 256, 0, stream>>>(cw1, cw2, cw3, w2,
                                               wf1h, wf1l, wf2h, wf2l,
                                               wf3h, wf3l, w2q);
  // conv1: 224x224 -> 55x55(3025), OC=32, NPB=128, async-LDS staged (r13)
  conv1_kernel<<<dim3(24, 128), 256, 0, stream>>>(state, wf1h, wf1l, cb1, f1hl);
  // conv2: IC=32,KH=4,KWP=4,KWV=4,S=2, 55x55 -> 26x26(676), OC=64, NPB=64
  convhl_kernel<32, 4, 4, 4, 2, 55, 55, 26, 676, 64, 64, false>
      <<<dim3(11, 128), 256, 0, stream>>>(f1hl, wf2h, wf2l, cb2, (void*)f2hl);
  // conv3: IC=64,KH=3,KWP=4,KWV=3,S=1, 26x26 -> 24x24(576), OC=64, NPB=64 -> x
  convhl_kernel<64, 3, 4, 3, 1, 26, 26, 24, 576, 64, 64, true>
      <<<dim3(9, 128), 256, 0, stream>>>(f2hl, wf3h, wf3l, cb3, (void*)xb);
  histpack_kernel<<<48, 256, 0, stream>>>(history, xb);
  fc1_kernel<<<FC1_KT * 4, 256, 0, stream>>>(xb, w1, P);
  reduce_p_kernel<<<256, 64, 0, stream>>>(P, b1, h1s);
  recur_kernel<<<128, 256, 0, stream>>>(h1s, (const float4*)w2q, b2, w3, b3, out);
}

// Round 10
// 319.872 us; speedup vs baseline: 1.2440x; 1.0055x over previous
//
#include <hip/hip_runtime.h>

#define ALPHA 0.9f
#define BETA  0.8f
#define XS 36960   // padded row stride for x

typedef _Float16 f16;
typedef _Float16 f16x8 __attribute__((ext_vector_type(8)));
typedef float f32x4 __attribute__((ext_vector_type(4)));
typedef unsigned int u32;

// 16B load at only-4B-known alignment (w1 rows stride 36954 floats -> odd
// rows are 8B-aligned). Backend emits unaligned wide loads; same bytes.
struct F4 { float x, y, z, w; };   // alignof = 4

// async global->LDS DMA, 16B per lane: per-lane global src, wave-uniform LDS
// base + lane*16 dest (m97 pattern).
#define GLOAD_LDS16(gsrc, ldst)                                        \
  __builtin_amdgcn_global_load_lds(                                    \
      (const __attribute__((address_space(1))) void*)(gsrc),           \
      (__attribute__((address_space(3))) void*)(ldst), 16, 0, 0)

// de-interleave (h,l)-pair dwords: hpair = h1<<16|h0, lpair = l1<<16|l0
__device__ inline u32 hpair(u32 d0, u32 d1) {
#if __has_builtin(__builtin_amdgcn_perm)
  return __builtin_amdgcn_perm(d1, d0, 0x05040100u);
#else
  return (d0 & 0xffffu) | (d1 << 16);
#endif
}
__device__ inline u32 lpair(u32 d0, u32 d1) {
#if __has_builtin(__builtin_amdgcn_perm)
  return __builtin_amdgcn_perm(d1, d0, 0x07060302u);
#else
  return (d0 >> 16) | (d1 & 0xffff0000u);
#endif
}

// split fp32 -> packed (h,l) f16-pair dword (exact same h/l values as the
// old consumer-side split: h=f16(v), l=f16(v-h))
__device__ inline u32 pack_hl(float v) {
  f16 h = (f16)v;
  f16 l = (f16)(v - (float)h);
  return (u32)__builtin_bit_cast(unsigned short, h) |
         ((u32)__builtin_bit_cast(unsigned short, l) << 16);
}

// ---------------------------------------------------------------------------
// state: 128x3x224x224  conv1 32x3x8x8 s4 -> f1hl (hl-pair) 128x32x55x55
// f1hl -> conv2 64x32x4x4 s2 -> f2hl (hl-pair) 128x64x26x26
// f2hl -> conv3 64x64x3x3 s1 -> x rows fp32 (36864 + 90 history, pad 36960)
// Convs: split-f16 MFMA (hi+lo, 3 MFMAs/product, fp32-quality: absmax 0.0).
// r19: conv1 at 512 threads/block (8 waves, NPB=256). Across 6 variants
//   conv1 pinned at ~51us and ~49% occupancy (16 waves/CU); r14 (occ 27%
//   -> 72.7us) and r18 (fc1 occ fix -> -17.5us) establish time ~ resident
//   waves for these queue-bound gathers. 512-thread blocks: LDS 36KB -> 4
//   blocks/CU x 8 waves = 32 waves = 100% static occupancy. Pure index
//   rework (B regions 8->16); per-lane values and MFMA order unchanged ->
//   f1hl bitwise identical. Everything else r18 verbatim (321.6us best).
// ---------------------------------------------------------------------------

// Split conv weights into f16 hi/lo pairs; conv3 padded [oc][c][kh][4]
// (kw=3 -> 0). Repack w2 (256x128) -> w2q[k4][j] float4 columns.
__global__ __launch_bounds__(256) void prep_weights_kernel(
    const float* __restrict__ cw1, const float* __restrict__ cw2,
    const float* __restrict__ cw3, const float* __restrict__ w2,
    f16* __restrict__ w1h, f16* __restrict__ w1l,
    f16* __restrict__ w2h, f16* __restrict__ w2l,
    f16* __restrict__ w3h, f16* __restrict__ w3l,
    float* __restrict__ w2q) {
  int i = blockIdx.x * 256 + threadIdx.x;   // grid covers 49152
  if (i < 6144)  { float v = cw1[i]; f16 h = (f16)v; w1h[i] = h; w1l[i] = (f16)(v - (float)h); }
  if (i < 32768) { float v = cw2[i]; f16 h = (f16)v; w2h[i] = h; w2l[i] = (f16)(v - (float)h); }
  if (i < 49152) {
    int oc = i / 768, r = i % 768;
    int c = r / 12, rr = r % 12, kh = rr >> 2, kw = rr & 3;
    float v = (kw < 3) ? cw3[oc * 576 + c * 9 + kh * 3 + kw] : 0.f;
    f16 h = (f16)v; w3h[i] = h; w3l[i] = (f16)(v - (float)h);
  }
  if (i < 32768) {   // w2[j][k] -> w2q[(k4*256 + j)*4 + e]
    int j = i >> 7, k = i & 127;
    w2q[((k >> 2) * 256 + j) * 4 + (k & 3)] = w2[i];
  }
}

// ---------------------------------------------------------------------------
// conv1 (r19, 512 threads / 8 waves / NPB=256): 16x16x32 MFMA layouts
// (HW-verified): A[m=lane&15][k=quad*8+j], B[k=quad*8+j][n=lane&15],
// C col=lane&15 row=quad*4+reg.
// B slot s (0..1023): holds B[k=kt*32+((s>>4)&3)*8+j][npos=(s>>6)*16+(s&15)],
// raw fp32, staged by global_load_lds: wave w stages regions {w, 8+w}
// (si in {0,1}, s = t + si*512), lane l -> region*512 + half*256 + l*4.
// Wave w computes pos-tiles {2w, 2w+1}: reads its own lane's staged slots
// (same l index, same quad) -> values bitwise identical to the r13 scheme.
// Gathers 16B-aligned. Convert to split-f16 at fragment read.
// ---------------------------------------------------------------------------
__global__ __launch_bounds__(512) void conv1_kernel(
    const float* __restrict__ in, const f16* __restrict__ wh,
    const f16* __restrict__ wl, const float* __restrict__ bias,
    u32* __restrict__ out) {
  constexpr int K = 192, KCH = 6, OW = 55, OHW = 3025, NPB = 256;
  __shared__ __attribute__((aligned(16))) f16 Ah[2 * 512], Al[2 * 512]; // 4KB
  __shared__ __attribute__((aligned(16))) float Bf[16 * 512];           // 32KB

  const int n = blockIdx.y, pos0 = blockIdx.x * NPB;
  const int t = threadIdx.x;                 // 0..511
  const int w = t >> 6, lane = t & 63, quad = lane >> 4, l16 = lane & 15;
  const float* __restrict__ inb = in + (size_t)n * 3 * 224 * 224;

  // staging invariants: rq = k-quad this thread stages (same for both si)
  const int rq = (t >> 4) & 3;
  int base[2];
#pragma unroll
  for (int si = 0; si < 2; ++si) {
    int s = t + si * 512;                    // 0..1023
    int pos = pos0 + (s >> 6) * 16 + (s & 15);
    if (pos > OHW - 1) pos = OHW - 1;        // clamp (store masked later)
    int oh = pos / OW, ow = pos - oh * OW;
    base[si] = oh * 4 * 224 + ow * 4;
  }
  // A slot (t<128): oc am, k offset ak
  const int am = (t >> 6) * 16 + (t & 15);
  const int ak = ((t >> 4) & 3) * 8;

  int posv[2];
#pragma unroll
  for (int ntl = 0; ntl < 2; ++ntl)
    posv[ntl] = pos0 + (w * 2 + ntl) * 16 + l16;

  f32x4 acc[2][2] = {};

  for (int kt = 0; kt < KCH; ++kt) {
    __syncthreads();
    if (t < 128) {   // stage weights (tiny, plain)
      *(f16x8*)&Ah[t * 8] = *(const f16x8*)&wh[am * K + kt * 32 + ak];
      *(f16x8*)&Al[t * 8] = *(const f16x8*)&wl[am * K + kt * 32 + ak];
    }
    {  // async B staging: 4 global_load_lds per wave (regions w and 8+w)
      int r = kt * 4 + rq;
      int c = r >> 3, kh = r & 7;
      int rowoff = c * 50176 + kh * 224;
#pragma unroll
      for (int si = 0; si < 2; ++si)
#pragma unroll
        for (int half = 0; half < 2; ++half)
          GLOAD_LDS16(inb + rowoff + base[si] + half * 4,
                      &Bf[(si * 8 + w) * 512 + half * 256]);
    }
    __syncthreads();   // drains vmcnt: B in LDS, A visible

    f16x8 ah0 = *(const f16x8*)&Ah[0 * 512 + lane * 8];
    f16x8 ah1 = *(const f16x8*)&Ah[1 * 512 + lane * 8];
    f16x8 al0 = *(const f16x8*)&Al[0 * 512 + lane * 8];
    f16x8 al1 = *(const f16x8*)&Al[1 * 512 + lane * 8];
    f16x8 bh[2], bl[2];
#pragma unroll
    for (int ntl = 0; ntl < 2; ++ntl) {
      const float* bp = &Bf[(w * 2 + ntl) * 512 + lane * 4];
      float4 v0 = *(const float4*)bp;
      float4 v1 = *(const float4*)(bp + 256);
      float vv[8] = {v0.x, v0.y, v0.z, v0.w, v1.x, v1.y, v1.z, v1.w};
#pragma unroll
      for (int e = 0; e < 8; ++e) {
        f16 h = (f16)vv[e];
        bh[ntl][e] = h;
        bl[ntl][e] = (f16)(vv[e] - (float)h);
      }
    }
    acc[0][0] = __builtin_amdgcn_mfma_f32_16x16x32_f16(ah0, bh[0], acc[0][0], 0, 0, 0);
    acc[0][0] = __builtin_amdgcn_mfma_f32_16x16x32_f16(ah0, bl[0], acc[0][0], 0, 0, 0);
    acc[0][0] = __builtin_amdgcn_mfma_f32_16x16x32_f16(al0, bh[0], acc[0][0], 0, 0, 0);
    acc[1][0] = __builtin_amdgcn_mfma_f32_16x16x32_f16(ah1, bh[0], acc[1][0], 0, 0, 0);
    acc[1][0] = __builtin_amdgcn_mfma_f32_16x16x32_f16(ah1, bl[0], acc[1][0], 0, 0, 0);
    acc[1][0] = __builtin_amdgcn_mfma_f32_16x16x32_f16(al1, bh[0], acc[1][0], 0, 0, 0);
    acc[0][1] = __builtin_amdgcn_mfma_f32_16x16x32_f16(ah0, bh[1], acc[0][1], 0, 0, 0);
    acc[0][1] = __builtin_amdgcn_mfma_f32_16x16x32_f16(ah0, bl[1], acc[0][1], 0, 0, 0);
    acc[0][1] = __builtin_amdgcn_mfma_f32_16x16x32_f16(al0, bh[1], acc[0][1], 0, 0, 0);
    acc[1][1] = __builtin_amdgcn_mfma_f32_16x16x32_f16(ah1, bh[1], acc[1][1], 0, 0, 0);
    acc[1][1] = __builtin_amdgcn_mfma_f32_16x16x32_f16(ah1, bl[1], acc[1][1], 0, 0, 0);
    acc[1][1] = __builtin_amdgcn_mfma_f32_16x16x32_f16(al1, bh[1], acc[1][1], 0, 0, 0);
  }

#pragma unroll
  for (int mtl = 0; mtl < 2; ++mtl)
#pragma unroll
    for (int ntl = 0; ntl < 2; ++ntl)
#pragma unroll
      for (int r = 0; r < 4; ++r) {
        int oc  = mtl * 16 + quad * 4 + r;
        int pos = posv[ntl];
        if (pos < OHW) {
          float v = acc[mtl][ntl][r] + bias[oc];
          v = v > 0.f ? v : 0.f;
          out[((size_t)n * 32 + oc) * OHW + pos] = pack_hl(v);
        }
      }
}

// ---------------------------------------------------------------------------
// conv2/conv3 (r13 form): input packed (h,l)-pair dwords -> staging is a pure
// dword copy (8 independent loads/thread, no conversion), de-interleave at
// fragment read via v_perm (2 ops per pair). OC=64, NPB=64: MTILES=NTILES=4,
// WOC=2 (waves {0,1} oc-half, {2,3}; wpos = w>>1).
// ---------------------------------------------------------------------------
template<int IC, int KH, int KWP, int KWV, int S, int IH, int IW,
         int OW, int OHW, int OC, int NPB, bool OUT_X>
__global__ __launch_bounds__(256) void convhl_kernel(
    const u32* __restrict__ in, const f16* __restrict__ wh,
    const f16* __restrict__ wl, const float* __restrict__ bias,
    void* __restrict__ outv) {
  constexpr int K = IC * KH * KWP;      // 512 / 768
  constexpr int KCH = K / 32;           // 16 / 24
  __shared__ __attribute__((aligned(16))) f16 Ah[4 * 512], Al[4 * 512]; // 8KB
  __shared__ __attribute__((aligned(16))) u32 Bhl[2][256 * 4];          // 8KB

  const int n = blockIdx.y, pos0 = blockIdx.x * NPB;
  const int t = threadIdx.x;
  const int w = t >> 6, lane = t & 63, quad = lane >> 4, l16 = lane & 15;
  const int woc = w & 1, wpos = w >> 1;
  const u32* __restrict__ inb = in + (size_t)n * IC * IH * IW;

  // B slot s = t: npos = (t>>6)*16 + (t&15); k-rows kt*8 + rq + half
  int pos = pos0 + (t >> 6) * 16 + (t & 15);
  if (pos > OHW - 1) pos = OHW - 1;      // clamp (store masked later)
  int oh = pos / OW, ow = pos - oh * OW;
  const int ohS = oh * S, owS = ow * S;
  const int rq = ((t >> 4) & 3) * 2;
  const int am = (t >> 6) * 16 + (t & 15);
  const int ak = ((t >> 4) & 3) * 8;

  int posv[2];
#pragma unroll
  for (int ntl = 0; ntl < 2; ++ntl)
    posv[ntl] = pos0 + (wpos * 2 + ntl) * 16 + l16;

  f32x4 acc[2][2] = {};

  for (int kt = 0; kt < KCH; ++kt) {
    __syncthreads();
    // stage weights: 8 consecutive k for one oc (all 256 threads)
    *(f16x8*)&Ah[t * 8] = *(const f16x8*)&wh[am * K + kt * 32 + ak];
    *(f16x8*)&Al[t * 8] = *(const f16x8*)&wl[am * K + kt * 32 + ak];
    // stage B: pure hl-dword gather, 4 dwords per half
#pragma unroll
    for (int half = 0; half < 2; ++half) {
      int row = kt * 8 + rq + half;
      int c = row / KH, kh = row - c * KH;
      const u32* p = inb + ((size_t)c * IH + ohS + kh) * IW + owS;
      uint4 d;
      d.x = p[0]; d.y = p[1]; d.z = p[2];
      d.w = (KWV < KWP) ? 0u : p[3];       // conv3: padded kw=3 -> 0
      *(uint4*)&Bhl[half][t * 4] = d;
    }
    __syncthreads();

    f16x8 ah0 = *(const f16x8*)&Ah[(woc * 2 + 0) * 512 + lane * 8];
    f16x8 ah1 = *(const f16x8*)&Ah[(woc * 2 + 1) * 512 + lane * 8];
    f16x8 al0 = *(const f16x8*)&Al[(woc * 2 + 0) * 512 + lane * 8];
    f16x8 al1 = *(const f16x8*)&Al[(woc * 2 + 1) * 512 + lane * 8];
    f16x8 bh[2], bl[2];
#pragma unroll
    for (int ntl = 0; ntl < 2; ++ntl) {
      int sl = ((wpos * 2 + ntl) * 64 + lane) * 4;
      uint4 q0 = *(const uint4*)&Bhl[0][sl];
      uint4 q1 = *(const uint4*)&Bhl[1][sl];
      uint4 hv, lv;
      hv.x = hpair(q0.x, q0.y); lv.x = lpair(q0.x, q0.y);
      hv.y = hpair(q0.z, q0.w); lv.y = lpair(q0.z, q0.w);
      hv.z = hpair(q1.x, q1.y); lv.z = lpair(q1.x, q1.y);
      hv.w = hpair(q1.z, q1.w); lv.w = lpair(q1.z, q1.w);
      bh[ntl] = __builtin_bit_cast(f16x8, hv);
      bl[ntl] = __builtin_bit_cast(f16x8, lv);
    }
    acc[0][0] = __builtin_amdgcn_mfma_f32_16x16x32_f16(ah0, bh[0], acc[0][0], 0, 0, 0);
    acc[0][0] = __builtin_amdgcn_mfma_f32_16x16x32_f16(ah0, bl[0], acc[0][0], 0, 0, 0);
    acc[0][0] = __builtin_amdgcn_mfma_f32_16x16x32_f16(al0, bh[0], acc[0][0], 0, 0, 0);
    acc[1][0] = __builtin_amdgcn_mfma_f32_16x16x32_f16(ah1, bh[0], acc[1][0], 0, 0, 0);
    acc[1][0] = __builtin_amdgcn_mfma_f32_16x16x32_f16(ah1, bl[0], acc[1][0], 0, 0, 0);
    acc[1][0] = __builtin_amdgcn_mfma_f32_16x16x32_f16(al1, bh[0], acc[1][0], 0, 0, 0);
    acc[0][1] = __builtin_amdgcn_mfma_f32_16x16x32_f16(ah0, bh[1], acc[0][1], 0, 0, 0);
    acc[0][1] = __builtin_amdgcn_mfma_f32_16x16x32_f16(ah0, bl[1], acc[0][1], 0, 0, 0);
    acc[0][1] = __builtin_amdgcn_mfma_f32_16x16x32_f16(al0, bh[1], acc[0][1], 0, 0, 0);
    acc[1][1] = __builtin_amdgcn_mfma_f32_16x16x32_f16(ah1, bh[1], acc[1][1], 0, 0, 0);
    acc[1][1] = __builtin_amdgcn_mfma_f32_16x16x32_f16(ah1, bl[1], acc[1][1], 0, 0, 0);
    acc[1][1] = __builtin_amdgcn_mfma_f32_16x16x32_f16(al1, bh[1], acc[1][1], 0, 0, 0);
  }

#pragma unroll
  for (int mtl = 0; mtl < 2; ++mtl)
#pragma unroll
    for (int ntl = 0; ntl < 2; ++ntl)
#pragma unroll
      for (int r = 0; r < 4; ++r) {
        int oc = (woc * 2 + mtl) * 16 + quad * 4 + r;
        int p2 = posv[ntl];
        if (p2 < OHW) {
          float v = acc[mtl][ntl][r] + bias[oc];
          v = v > 0.f ? v : 0.f;
          if constexpr (OUT_X)
            ((float*)outv)[(size_t)n * XS + oc * OHW + p2] = v;
          else
            ((u32*)outv)[((size_t)n * OC + oc) * OHW + p2] = pack_hl(v);
        }
      }
}

// history -> x[:, 36864:36954], zero the pad to 36960
__global__ __launch_bounds__(256) void histpack_kernel(
    const float* __restrict__ h, float* __restrict__ x) {
  int i = blockIdx.x * 256 + threadIdx.x;
  if (i < 128 * 96) {
    int n = i / 96, k = i % 96;
    x[(size_t)n * XS + 36864 + k] = (k < 90) ? h[n * 90 + k] : 0.f;
  }
}

// FC1 (fp32): register-blocked split-K GEMM. r18: 32b x 128j tile per block
// (batch split x4, grid FC1_KT*4) for occupancy; K-chunking UNchanged so
// every (b,j,kt) partial keeps its unbroken kk FMA chain -> P bitwise
// identical to the 128b-tile version. Reads w1 directly (align-4 loads,
// explicit zeros at the K boundary).
#define FC1_KT 289
__global__ __launch_bounds__(256) void fc1_kernel(
    const float* __restrict__ x, const float* __restrict__ w1,
    float* __restrict__ P) {
  int kt = blockIdx.x >> 2;       // 0..288
  int b4 = blockIdx.x & 3;        // batch quarter (32 rows)
  int t  = threadIdx.x;
  int bq = t & 3, jq = t >> 2;    // bq 0..3, jq 0..63
  __shared__ float xs[32 * 36];
  __shared__ float wsm[128 * 36];
  float acc[8][2];
#pragma unroll
  for (int bb = 0; bb < 8; ++bb)
#pragma unroll
    for (int jj = 0; jj < 2; ++jj) acc[bb][jj] = 0.f;

  int cs = t & 7;          // float4 column for staging (0..7)
  int rs = t >> 3;         // row for staging (0..31)
#pragma unroll 1
  for (int s = 0; s < 4; ++s) {
    int k0 = kt * 128 + s * 32;
    int gk = k0 + cs * 4;
    __syncthreads();
    {  // stage x: 32 rows (global b4*32 + rs), one float4/thread
      float4 xv;
      if (gk < 36954)      // x pad [36954,36960) is zeros -> float4 safe
        xv = *(const float4*)&x[(size_t)(b4 * 32 + rs) * XS + gk];
      else
        xv = make_float4(0.f, 0.f, 0.f, 0.f);
      *(float4*)&xs[rs * 36 + cs * 4] = xv;
    }
#pragma unroll
    for (int p = 0; p < 4; ++p) {  // stage w1: 128 rows, 4 passes
      int r = rs + p * 32;
      float4 wv;
      if (gk + 4 <= 36954) {
        F4 u = *(const F4*)&w1[(size_t)r * 36954 + gk];
        wv = make_float4(u.x, u.y, u.z, u.w);
      } else if (gk < 36954) {     // boundary tile (gk = 36952)
        wv.x = w1[(size_t)r * 36954 + gk];
        wv.y = (gk + 1 < 36954) ? w1[(size_t)r * 36954 + gk + 1] : 0.f;
        wv.z = 0.f; wv.w = 0.f;
      } else {
        wv = make_float4(0.f, 0.f, 0.f, 0.f);
      }
      *(float4*)&wsm[r * 36 + cs * 4] = wv;
    }
    __syncthreads();
#pragma unroll 1
    for (int kk = 0; kk < 32; kk += 4) {
      float4 xv[8], wv[2];
#pragma unroll
      for (int i = 0; i < 8; ++i)
        xv[i] = *(const float4*)&xs[(bq + 4 * i) * 36 + kk];
#pragma unroll
      for (int i = 0; i < 2; ++i)
        wv[i] = *(const float4*)&wsm[(jq + 64 * i) * 36 + kk];
#pragma unroll
      for (int bb = 0; bb < 8; ++bb)
#pragma unroll
        for (int jj = 0; jj < 2; ++jj) {
          acc[bb][jj] = fmaf(xv[bb].x, wv[jj].x, acc[bb][jj]);
          acc[bb][jj] = fmaf(xv[bb].y, wv[jj].y, acc[bb][jj]);
          acc[bb][jj] = fmaf(xv[bb].z, wv[jj].z, acc[bb][jj]);
          acc[bb][jj] = fmaf(xv[bb].w, wv[jj].w, acc[bb][jj]);
        }
    }
  }
  float* Pb = P + (size_t)kt * 16384;
#pragma unroll
  for (int bb = 0; bb < 8; ++bb)
#pragma unroll
    for (int jj = 0; jj < 2; ++jj)
      Pb[(b4 * 32 + bq + 4 * bb) * 128 + jq + 64 * jj] = acc[bb][jj];
}

// Reduce P over kt: h1s[b][j] = sum_kt P[kt][b][j] + b1[j].
// 32 loads in flight per thread (order-preserving: per-accumulator add
// sequences identical to the 4-accumulator loop), 256 blocks x 1 wave.
__global__ __launch_bounds__(64) void reduce_p_kernel(
    const float* __restrict__ P, const float* __restrict__ b1,
    float* __restrict__ h1s) {
  int idx = blockIdx.x * 64 + threadIdx.x;   // 0..16383
  int j = idx & 127;
  float a0 = 0.f, a1 = 0.f, a2 = 0.f, a3 = 0.f;
  int kt = 0;
  for (; kt + 31 < FC1_KT; kt += 32) {
    float v[32];
#pragma unroll
    for (int q = 0; q < 32; ++q)
      v[q] = P[(size_t)(kt + q) * 16384 + idx];
#pragma unroll
    for (int q = 0; q < 32; q += 4) {
      a0 += v[q]; a1 += v[q + 1]; a2 += v[q + 2]; a3 += v[q + 3];
    }
  }
  for (; kt + 3 < FC1_KT; kt += 4) {
    a0 += P[(size_t)(kt + 0) * 16384 + idx];
    a1 += P[(size_t)(kt + 1) * 16384 + idx];
    a2 += P[(size_t)(kt + 2) * 16384 + idx];
    a3 += P[(size_t)(kt + 3) * 16384 + idx];
  }
  for (; kt < FC1_KT; ++kt) a0 += P[(size_t)kt * 16384 + idx];
  h1s[idx] = ((a0 + a1) + (a2 + a3)) + b1[j];
}

// Recurrence: one block per batch row. w2 column in VGPRs (loaded once,
// 32 coalesced dwordx4); spk broadcast via LDS; w3 staged in LDS; layer3
// as 144-thread partials + 9-thread reduce. Critical path ~700 cyc/step.
__global__ __launch_bounds__(256, 1) void recur_kernel(
    const float* __restrict__ h1s,  // [128][128]
    const float4* __restrict__ w2q, // [32][256] float4 cols: w2q[k4*256+j]
    const float* __restrict__ b2,
    const float* __restrict__ w3,   // [9][256]
    const float* __restrict__ b3,
    float* __restrict__ out) {      // [128][9]
  int b = blockIdx.x;
  int t = threadIdx.x;
  __shared__ float spk1s[128];
  __shared__ float spk2s[256];
  __shared__ float w3s[9 * 256];
  __shared__ float part[9][16];
  float4 w2c[32];
#pragma unroll
  for (int k4 = 0; k4 < 32; ++k4) w2c[k4] = w2q[k4 * 256 + t];
  for (int i = t; i < 9 * 256; i += 256) w3s[i] = w3[i];
  float h1 = (t < 128) ? h1s[b * 128 + t] : 0.f;
  float mem1 = 0.f, syn1 = 0.f, mem2 = 0.f, syn2 = 0.f;
  float b2v = b2[t];
  float mem3 = 0.f, syn3 = 0.f, pot = 0.f;
  float b3v = (t < 9) ? b3[t] : 0.f;
  int j3 = t >> 4, p = t & 15;      // layer3 partial owners (t < 144)
  __syncthreads();                  // w3s ready

  for (int step = 0; step < 10; ++step) {
    if (t < 128) {
      syn1 = ALPHA * syn1 + h1;
      mem1 = BETA * mem1 + syn1;
      float s = (mem1 > 1.0f) ? 1.0f : 0.0f;
      mem1 -= s;
      spk1s[t] = s;
    }
    __syncthreads();
    float h2 = b2v;
#pragma unroll
    for (int k4 = 0; k4 < 32; ++k4) {
      float4 s = *(const float4*)&spk1s[k4 * 4];   // broadcast read
      h2 = fmaf(s.x, w2c[k4].x, h2);
      h2 = fmaf(s.y, w2c[k4].y, h2);
      h2 = fmaf(s.z, w2c[k4].z, h2);
      h2 = fmaf(s.w, w2c[k4].w, h2);
    }
    syn2 = ALPHA * syn2 + h2;
    mem2 = BETA * mem2 + syn2;
    float s2 = (mem2 > 1.0f) ? 1.0f : 0.0f;
    mem2 -= s2;
    spk2s[t] = s2;
    __syncthreads();
    if (t < 144) {
      float a = 0.f;
      const float* wr = &w3s[j3 * 256 + p * 16];
      const float* sp = &spk2s[p * 16];
#pragma unroll
      for (int e = 0; e < 16; ++e) a = fmaf(sp[e], wr[e], a);
      part[j3][p] = a;
    }
    __syncthreads();
    if (t < 9) {
      float a = b3v;
#pragma unroll
      for (int p2 = 0; p2 < 16; ++p2) a += part[t][p2];
      syn3 = ALPHA * syn3 + a;
      mem3 = BETA * mem3 + syn3;
      pot += mem3;
    }
  }
  if (t < 9) out[b * 9 + t] = pot * 0.1f;
}

extern "C" void kernel_launch(void* const* d_in, const int* in_sizes, int n_in,
                              void* d_out, int out_size, void* d_ws, size_t ws_size,
                              hipStream_t stream) {
  const float* state   = (const float*)d_in[0];
  const float* history = (const float*)d_in[1];
  const float* cw1 = (const float*)d_in[2];
  const float* cb1 = (const float*)d_in[3];
  const float* cw2 = (const float*)d_in[4];
  const float* cb2 = (const float*)d_in[5];
  const float* cw3 = (const float*)d_in[6];
  const float* cb3 = (const float*)d_in[7];
  const float* w1  = (const float*)d_in[8];
  const float* b1  = (const float*)d_in[9];
  const float* w2  = (const float*)d_in[10];
  const float* b2  = (const float*)d_in[11];
  const float* w3  = (const float*)d_in[12];
  const float* b3  = (const float*)d_in[13];
  float* out = (float*)d_out;
  char* ws = (char*)d_ws;

  // workspace (bytes), time-multiplexed:
  //  f1hl  [0, 49,561,600)              conv1 -> conv2  (hl-pair dwords)
  //    xb  [0, 18,923,520)              conv3 -> fc1    (f1hl dead)
  //  f2hl  [49,561,600, 71,712,768)     conv2 -> conv3  (hl-pair dwords)
  //    P   [49,561,600, 68,501,504)     fc1 -> reduce   (f2hl dead)
  //  small weights [71,712,768, 72,261,632)
  u32*   f1hl = (u32*)(ws + 0);
  float* xb   = (float*)(ws + 0);
  u32*   f2hl = (u32*)(ws + 49561600);
  float* P    = (float*)(ws + 49561600);
  f16* wf1h = (f16*)(ws + 71712768);   // 12,288
  f16* wf1l = (f16*)(ws + 71725056);   // 12,288
  f16* wf2h = (f16*)(ws + 71737344);   // 65,536
  f16* wf2l = (f16*)(ws + 71802880);   // 65,536
  f16* wf3h = (f16*)(ws + 71868416);   // 98,304 (padded K=768)
  f16* wf3l = (f16*)(ws + 71966720);   // 98,304
  float* w2q = (float*)(ws + 72065024);  // 131,072
  float* h1s = (float*)(ws + 72196096);  // 65,536 (end 72,261,632)

  prep_weights_kernel<<<192, 256, 0, stream>>>(cw1, cw2, cw3, w2,
                                               wf1h, wf1l, wf2h, wf2l,
                                               wf3h, wf3l, w2q);
  // conv1: 224x224 -> 55x55(3025), OC=32, NPB=256, 512 threads (r19)
  conv1_kernel<<<dim3(12, 128), 512, 0, stream>>>(state, wf1h, wf1l, cb1, f1hl);
  // conv2: IC=32,KH=4,KWP=4,KWV=4,S=2, 55x55 -> 26x26(676), OC=64, NPB=64
  convhl_kernel<32, 4, 4, 4, 2, 55, 55, 26, 676, 64, 64, false>
      <<<dim3(11, 128), 256, 0, stream>>>(f1hl, wf2h, wf2l, cb2, (void*)f2hl);
  // conv3: IC=64,KH=3,KWP=4,KWV=3,S=1, 26x26 -> 24x24(576), OC=64, NPB=64 -> x
  convhl_kernel<64, 3, 4, 3, 1, 26, 26, 24, 576, 64, 64, true>
      <<<dim3(9, 128), 256, 0, stream>>>(f2hl, wf3h, wf3l, cb3, (void*)xb);
  histpack_kernel<<<48, 256, 0, stream>>>(history, xb);
  fc1_kernel<<<FC1_KT * 4, 256, 0, stream>>>(xb, w1, P);
  reduce_p_kernel<<<256, 64, 0, stream>>>(P, b1, h1s);
  recur_kernel<<<128, 256, 0, stream>>>(h1s, (const float4*)w2q, b2, w3, b3, out);
}

// Round 11
// 304.392 us; speedup vs baseline: 1.3073x; 1.0509x over previous
//
#include <hip/hip_runtime.h>

#define ALPHA 0.9f
#define BETA  0.8f
#define XS 36960   // padded row stride for x

typedef _Float16 f16;
typedef _Float16 f16x8 __attribute__((ext_vector_type(8)));
typedef float f32x4 __attribute__((ext_vector_type(4)));
typedef unsigned int u32;

// 16B load at only-4B-known alignment (w1 rows stride 36954 floats -> odd
// rows are 8B-aligned). Backend emits unaligned wide loads; same bytes.
struct F4 { float x, y, z, w; };   // alignof = 4

// async global->LDS DMA, 16B per lane: per-lane global src, wave-uniform LDS
// base + lane*16 dest (m97 pattern).
#define GLOAD_LDS16(gsrc, ldst)                                        \
  __builtin_amdgcn_global_load_lds(                                    \
      (const __attribute__((address_space(1))) void*)(gsrc),           \
      (__attribute__((address_space(3))) void*)(ldst), 16, 0, 0)

// de-interleave (h,l)-pair dwords: hpair = h1<<16|h0, lpair = l1<<16|l0
__device__ inline u32 hpair(u32 d0, u32 d1) {
#if __has_builtin(__builtin_amdgcn_perm)
  return __builtin_amdgcn_perm(d1, d0, 0x05040100u);
#else
  return (d0 & 0xffffu) | (d1 << 16);
#endif
}
__device__ inline u32 lpair(u32 d0, u32 d1) {
#if __has_builtin(__builtin_amdgcn_perm)
  return __builtin_amdgcn_perm(d1, d0, 0x07060302u);
#else
  return (d0 >> 16) | (d1 & 0xffff0000u);
#endif
}

// split fp32 -> packed (h,l) f16-pair dword (exact same h/l values as the
// old consumer-side split: h=f16(v), l=f16(v-h))
__device__ inline u32 pack_hl(float v) {
  f16 h = (f16)v;
  f16 l = (f16)(v - (float)h);
  return (u32)__builtin_bit_cast(unsigned short, h) |
         ((u32)__builtin_bit_cast(unsigned short, l) << 16);
}

// ---------------------------------------------------------------------------
// state: 128x3x224x224  conv1 32x3x8x8 s4 -> f1hl (hl-pair) 128x32x55x55
// f1hl -> conv2 64x32x4x4 s2 -> f2hl (hl-pair) 128x64x26x26
// f2hl -> conv3 64x64x3x3 s1 -> x rows fp32 (36864 + 90 history, pad 36960)
// Convs: split-f16 MFMA (hi+lo, 3 MFMAs/product, fp32-quality: absmax 0.0).
// r20: apply the r19 transform (NPB x2, 512 threads, 8 waves/block) to
//   conv2/conv3. conv2 measured 48us @ 31% occupancy, 1.35 TB/s, MfmaUtil
//   13% -- same latency/TLP-bound regime conv1 was in. Doubling positions
//   per block halves barrier-drain events per output element, improves
//   horizontal gather reuse (conv1: FETCH -17%), and 8-wave blocks raise
//   resident waves (3 blocks/CU x 8 = 24). Per-output math and k-order
//   unchanged -> f2hl/xb bitwise identical. Rest = r19 (319.9us best).
// ---------------------------------------------------------------------------

// Split conv weights into f16 hi/lo pairs; conv3 padded [oc][c][kh][4]
// (kw=3 -> 0). Repack w2 (256x128) -> w2q[k4][j] float4 columns.
__global__ __launch_bounds__(256) void prep_weights_kernel(
    const float* __restrict__ cw1, const float* __restrict__ cw2,
    const float* __restrict__ cw3, const float* __restrict__ w2,
    f16* __restrict__ w1h, f16* __restrict__ w1l,
    f16* __restrict__ w2h, f16* __restrict__ w2l,
    f16* __restrict__ w3h, f16* __restrict__ w3l,
    float* __restrict__ w2q) {
  int i = blockIdx.x * 256 + threadIdx.x;   // grid covers 49152
  if (i < 6144)  { float v = cw1[i]; f16 h = (f16)v; w1h[i] = h; w1l[i] = (f16)(v - (float)h); }
  if (i < 32768) { float v = cw2[i]; f16 h = (f16)v; w2h[i] = h; w2l[i] = (f16)(v - (float)h); }
  if (i < 49152) {
    int oc = i / 768, r = i % 768;
    int c = r / 12, rr = r % 12, kh = rr >> 2, kw = rr & 3;
    float v = (kw < 3) ? cw3[oc * 576 + c * 9 + kh * 3 + kw] : 0.f;
    f16 h = (f16)v; w3h[i] = h; w3l[i] = (f16)(v - (float)h);
  }
  if (i < 32768) {   // w2[j][k] -> w2q[(k4*256 + j)*4 + e]
    int j = i >> 7, k = i & 127;
    w2q[((k >> 2) * 256 + j) * 4 + (k & 3)] = w2[i];
  }
}

// ---------------------------------------------------------------------------
// conv1 (r19, 512 threads / 8 waves / NPB=256): 16x16x32 MFMA layouts
// (HW-verified): A[m=lane&15][k=quad*8+j], B[k=quad*8+j][n=lane&15],
// C col=lane&15 row=quad*4+reg.
// B slot s (0..1023): holds B[k=kt*32+((s>>4)&3)*8+j][npos=(s>>6)*16+(s&15)],
// raw fp32, staged by global_load_lds: wave w stages regions {w, 8+w}
// (si in {0,1}, s = t + si*512), lane l -> region*512 + half*256 + l*4.
// Wave w computes pos-tiles {2w, 2w+1}: reads its own lane's staged slots.
// Gathers 16B-aligned. Convert to split-f16 at fragment read.
// ---------------------------------------------------------------------------
__global__ __launch_bounds__(512) void conv1_kernel(
    const float* __restrict__ in, const f16* __restrict__ wh,
    const f16* __restrict__ wl, const float* __restrict__ bias,
    u32* __restrict__ out) {
  constexpr int K = 192, KCH = 6, OW = 55, OHW = 3025, NPB = 256;
  __shared__ __attribute__((aligned(16))) f16 Ah[2 * 512], Al[2 * 512]; // 4KB
  __shared__ __attribute__((aligned(16))) float Bf[16 * 512];           // 32KB

  const int n = blockIdx.y, pos0 = blockIdx.x * NPB;
  const int t = threadIdx.x;                 // 0..511
  const int w = t >> 6, lane = t & 63, quad = lane >> 4, l16 = lane & 15;
  const float* __restrict__ inb = in + (size_t)n * 3 * 224 * 224;

  // staging invariants: rq = k-quad this thread stages (same for both si)
  const int rq = (t >> 4) & 3;
  int base[2];
#pragma unroll
  for (int si = 0; si < 2; ++si) {
    int s = t + si * 512;                    // 0..1023
    int pos = pos0 + (s >> 6) * 16 + (s & 15);
    if (pos > OHW - 1) pos = OHW - 1;        // clamp (store masked later)
    int oh = pos / OW, ow = pos - oh * OW;
    base[si] = oh * 4 * 224 + ow * 4;
  }
  // A slot (t<128): oc am, k offset ak
  const int am = (t >> 6) * 16 + (t & 15);
  const int ak = ((t >> 4) & 3) * 8;

  int posv[2];
#pragma unroll
  for (int ntl = 0; ntl < 2; ++ntl)
    posv[ntl] = pos0 + (w * 2 + ntl) * 16 + l16;

  f32x4 acc[2][2] = {};

  for (int kt = 0; kt < KCH; ++kt) {
    __syncthreads();
    if (t < 128) {   // stage weights (tiny, plain)
      *(f16x8*)&Ah[t * 8] = *(const f16x8*)&wh[am * K + kt * 32 + ak];
      *(f16x8*)&Al[t * 8] = *(const f16x8*)&wl[am * K + kt * 32 + ak];
    }
    {  // async B staging: 4 global_load_lds per wave (regions w and 8+w)
      int r = kt * 4 + rq;
      int c = r >> 3, kh = r & 7;
      int rowoff = c * 50176 + kh * 224;
#pragma unroll
      for (int si = 0; si < 2; ++si)
#pragma unroll
        for (int half = 0; half < 2; ++half)
          GLOAD_LDS16(inb + rowoff + base[si] + half * 4,
                      &Bf[(si * 8 + w) * 512 + half * 256]);
    }
    __syncthreads();   // drains vmcnt: B in LDS, A visible

    f16x8 ah0 = *(const f16x8*)&Ah[0 * 512 + lane * 8];
    f16x8 ah1 = *(const f16x8*)&Ah[1 * 512 + lane * 8];
    f16x8 al0 = *(const f16x8*)&Al[0 * 512 + lane * 8];
    f16x8 al1 = *(const f16x8*)&Al[1 * 512 + lane * 8];
    f16x8 bh[2], bl[2];
#pragma unroll
    for (int ntl = 0; ntl < 2; ++ntl) {
      const float* bp = &Bf[(w * 2 + ntl) * 512 + lane * 4];
      float4 v0 = *(const float4*)bp;
      float4 v1 = *(const float4*)(bp + 256);
      float vv[8] = {v0.x, v0.y, v0.z, v0.w, v1.x, v1.y, v1.z, v1.w};
#pragma unroll
      for (int e = 0; e < 8; ++e) {
        f16 h = (f16)vv[e];
        bh[ntl][e] = h;
        bl[ntl][e] = (f16)(vv[e] - (float)h);
      }
    }
    acc[0][0] = __builtin_amdgcn_mfma_f32_16x16x32_f16(ah0, bh[0], acc[0][0], 0, 0, 0);
    acc[0][0] = __builtin_amdgcn_mfma_f32_16x16x32_f16(ah0, bl[0], acc[0][0], 0, 0, 0);
    acc[0][0] = __builtin_amdgcn_mfma_f32_16x16x32_f16(al0, bh[0], acc[0][0], 0, 0, 0);
    acc[1][0] = __builtin_amdgcn_mfma_f32_16x16x32_f16(ah1, bh[0], acc[1][0], 0, 0, 0);
    acc[1][0] = __builtin_amdgcn_mfma_f32_16x16x32_f16(ah1, bl[0], acc[1][0], 0, 0, 0);
    acc[1][0] = __builtin_amdgcn_mfma_f32_16x16x32_f16(al1, bh[0], acc[1][0], 0, 0, 0);
    acc[0][1] = __builtin_amdgcn_mfma_f32_16x16x32_f16(ah0, bh[1], acc[0][1], 0, 0, 0);
    acc[0][1] = __builtin_amdgcn_mfma_f32_16x16x32_f16(ah0, bl[1], acc[0][1], 0, 0, 0);
    acc[0][1] = __builtin_amdgcn_mfma_f32_16x16x32_f16(al0, bh[1], acc[0][1], 0, 0, 0);
    acc[1][1] = __builtin_amdgcn_mfma_f32_16x16x32_f16(ah1, bh[1], acc[1][1], 0, 0, 0);
    acc[1][1] = __builtin_amdgcn_mfma_f32_16x16x32_f16(ah1, bl[1], acc[1][1], 0, 0, 0);
    acc[1][1] = __builtin_amdgcn_mfma_f32_16x16x32_f16(al1, bh[1], acc[1][1], 0, 0, 0);
  }

#pragma unroll
  for (int mtl = 0; mtl < 2; ++mtl)
#pragma unroll
    for (int ntl = 0; ntl < 2; ++ntl)
#pragma unroll
      for (int r = 0; r < 4; ++r) {
        int oc  = mtl * 16 + quad * 4 + r;
        int pos = posv[ntl];
        if (pos < OHW) {
          float v = acc[mtl][ntl][r] + bias[oc];
          v = v > 0.f ? v : 0.f;
          out[((size_t)n * 32 + oc) * OHW + pos] = pack_hl(v);
        }
      }
}

// ---------------------------------------------------------------------------
// conv2/conv3 (r20: NPB=128, 512 threads, 8 waves): input packed (h,l)-pair
// dwords -> staging is a pure dword copy (8 independent loads/thread, no
// conversion), de-interleave at fragment read via v_perm. OC=64: MTILES=4,
// NTILES=NPB/16=8. Waves: woc = w&1 (oc half), wpos = w>>1 (pos pair 0..3).
// B slot s = t (0..511): npos = (s>>6)*16 + (s&15). A staged by t<256.
// LDS 24KB. Per-output math and k-order identical to the 256-thread form.
// ---------------------------------------------------------------------------
template<int IC, int KH, int KWP, int KWV, int S, int IH, int IW,
         int OW, int OHW, int OC, int NPB, bool OUT_X>
__global__ __launch_bounds__(NPB * 4) void convhl_kernel(
    const u32* __restrict__ in, const f16* __restrict__ wh,
    const f16* __restrict__ wl, const float* __restrict__ bias,
    void* __restrict__ outv) {
  constexpr int K = IC * KH * KWP;      // 512 / 768
  constexpr int KCH = K / 32;           // 16 / 24
  constexpr int BS = NPB * 4;           // block size: 512
  __shared__ __attribute__((aligned(16))) f16 Ah[4 * 512], Al[4 * 512]; // 8KB
  __shared__ __attribute__((aligned(16))) u32 Bhl[2][BS * 4];           // 16KB

  const int n = blockIdx.y, pos0 = blockIdx.x * NPB;
  const int t = threadIdx.x;
  const int w = t >> 6, lane = t & 63, quad = lane >> 4, l16 = lane & 15;
  const int woc = w & 1, wpos = w >> 1;   // wpos 0..3
  const u32* __restrict__ inb = in + (size_t)n * IC * IH * IW;

  // B slot s = t: npos = (t>>6)*16 + (t&15); k-rows kt*8 + rq + half
  int pos = pos0 + (t >> 6) * 16 + (t & 15);
  if (pos > OHW - 1) pos = OHW - 1;      // clamp (store masked later)
  int oh = pos / OW, ow = pos - oh * OW;
  const int ohS = oh * S, owS = ow * S;
  const int rq = ((t >> 4) & 3) * 2;
  const int am = (t >> 6) * 16 + (t & 15);   // valid for t<256
  const int ak = ((t >> 4) & 3) * 8;

  int posv[2];
#pragma unroll
  for (int ntl = 0; ntl < 2; ++ntl)
    posv[ntl] = pos0 + (wpos * 2 + ntl) * 16 + l16;

  f32x4 acc[2][2] = {};

  for (int kt = 0; kt < KCH; ++kt) {
    __syncthreads();
    if (t < 256) {   // stage weights: 8 consecutive k for one oc
      *(f16x8*)&Ah[t * 8] = *(const f16x8*)&wh[am * K + kt * 32 + ak];
      *(f16x8*)&Al[t * 8] = *(const f16x8*)&wl[am * K + kt * 32 + ak];
    }
    // stage B: pure hl-dword gather, 4 dwords per half
#pragma unroll
    for (int half = 0; half < 2; ++half) {
      int row = kt * 8 + rq + half;
      int c = row / KH, kh = row - c * KH;
      const u32* p = inb + ((size_t)c * IH + ohS + kh) * IW + owS;
      uint4 d;
      d.x = p[0]; d.y = p[1]; d.z = p[2];
      d.w = (KWV < KWP) ? 0u : p[3];       // conv3: padded kw=3 -> 0
      *(uint4*)&Bhl[half][t * 4] = d;
    }
    __syncthreads();

    f16x8 ah0 = *(const f16x8*)&Ah[(woc * 2 + 0) * 512 + lane * 8];
    f16x8 ah1 = *(const f16x8*)&Ah[(woc * 2 + 1) * 512 + lane * 8];
    f16x8 al0 = *(const f16x8*)&Al[(woc * 2 + 0) * 512 + lane * 8];
    f16x8 al1 = *(const f16x8*)&Al[(woc * 2 + 1) * 512 + lane * 8];
    f16x8 bh[2], bl[2];
#pragma unroll
    for (int ntl = 0; ntl < 2; ++ntl) {
      int sl = ((wpos * 2 + ntl) * 64 + lane) * 4;
      uint4 q0 = *(const uint4*)&Bhl[0][sl];
      uint4 q1 = *(const uint4*)&Bhl[1][sl];
      uint4 hv, lv;
      hv.x = hpair(q0.x, q0.y); lv.x = lpair(q0.x, q0.y);
      hv.y = hpair(q0.z, q0.w); lv.y = lpair(q0.z, q0.w);
      hv.z = hpair(q1.x, q1.y); lv.z = lpair(q1.x, q1.y);
      hv.w = hpair(q1.z, q1.w); lv.w = lpair(q1.z, q1.w);
      bh[ntl] = __builtin_bit_cast(f16x8, hv);
      bl[ntl] = __builtin_bit_cast(f16x8, lv);
    }
    acc[0][0] = __builtin_amdgcn_mfma_f32_16x16x32_f16(ah0, bh[0], acc[0][0], 0, 0, 0);
    acc[0][0] = __builtin_amdgcn_mfma_f32_16x16x32_f16(ah0, bl[0], acc[0][0], 0, 0, 0);
    acc[0][0] = __builtin_amdgcn_mfma_f32_16x16x32_f16(al0, bh[0], acc[0][0], 0, 0, 0);
    acc[1][0] = __builtin_amdgcn_mfma_f32_16x16x32_f16(ah1, bh[0], acc[1][0], 0, 0, 0);
    acc[1][0] = __builtin_amdgcn_mfma_f32_16x16x32_f16(ah1, bl[0], acc[1][0], 0, 0, 0);
    acc[1][0] = __builtin_amdgcn_mfma_f32_16x16x32_f16(al1, bh[0], acc[1][0], 0, 0, 0);
    acc[0][1] = __builtin_amdgcn_mfma_f32_16x16x32_f16(ah0, bh[1], acc[0][1], 0, 0, 0);
    acc[0][1] = __builtin_amdgcn_mfma_f32_16x16x32_f16(ah0, bl[1], acc[0][1], 0, 0, 0);
    acc[0][1] = __builtin_amdgcn_mfma_f32_16x16x32_f16(al0, bh[1], acc[0][1], 0, 0, 0);
    acc[1][1] = __builtin_amdgcn_mfma_f32_16x16x32_f16(ah1, bh[1], acc[1][1], 0, 0, 0);
    acc[1][1] = __builtin_amdgcn_mfma_f32_16x16x32_f16(ah1, bl[1], acc[1][1], 0, 0, 0);
    acc[1][1] = __builtin_amdgcn_mfma_f32_16x16x32_f16(al1, bh[1], acc[1][1], 0, 0, 0);
  }

#pragma unroll
  for (int mtl = 0; mtl < 2; ++mtl)
#pragma unroll
    for (int ntl = 0; ntl < 2; ++ntl)
#pragma unroll
      for (int r = 0; r < 4; ++r) {
        int oc = (woc * 2 + mtl) * 16 + quad * 4 + r;
        int p2 = posv[ntl];
        if (p2 < OHW) {
          float v = acc[mtl][ntl][r] + bias[oc];
          v = v > 0.f ? v : 0.f;
          if constexpr (OUT_X)
            ((float*)outv)[(size_t)n * XS + oc * OHW + p2] = v;
          else
            ((u32*)outv)[((size_t)n * OC + oc) * OHW + p2] = pack_hl(v);
        }
      }
}

// history -> x[:, 36864:36954], zero the pad to 36960
__global__ __launch_bounds__(256) void histpack_kernel(
    const float* __restrict__ h, float* __restrict__ x) {
  int i = blockIdx.x * 256 + threadIdx.x;
  if (i < 128 * 96) {
    int n = i / 96, k = i % 96;
    x[(size_t)n * XS + 36864 + k] = (k < 90) ? h[n * 90 + k] : 0.f;
  }
}

// FC1 (fp32): register-blocked split-K GEMM. r18: 32b x 128j tile per block
// (batch split x4, grid FC1_KT*4) for occupancy; K-chunking UNchanged so
// every (b,j,kt) partial keeps its unbroken kk FMA chain -> P bitwise
// identical to the 128b-tile version. Reads w1 directly (align-4 loads,
// explicit zeros at the K boundary).
#define FC1_KT 289
__global__ __launch_bounds__(256) void fc1_kernel(
    const float* __restrict__ x, const float* __restrict__ w1,
    float* __restrict__ P) {
  int kt = blockIdx.x >> 2;       // 0..288
  int b4 = blockIdx.x & 3;        // batch quarter (32 rows)
  int t  = threadIdx.x;
  int bq = t & 3, jq = t >> 2;    // bq 0..3, jq 0..63
  __shared__ float xs[32 * 36];
  __shared__ float wsm[128 * 36];
  float acc[8][2];
#pragma unroll
  for (int bb = 0; bb < 8; ++bb)
#pragma unroll
    for (int jj = 0; jj < 2; ++jj) acc[bb][jj] = 0.f;

  int cs = t & 7;          // float4 column for staging (0..7)
  int rs = t >> 3;         // row for staging (0..31)
#pragma unroll 1
  for (int s = 0; s < 4; ++s) {
    int k0 = kt * 128 + s * 32;
    int gk = k0 + cs * 4;
    __syncthreads();
    {  // stage x: 32 rows (global b4*32 + rs), one float4/thread
      float4 xv;
      if (gk < 36954)      // x pad [36954,36960) is zeros -> float4 safe
        xv = *(const float4*)&x[(size_t)(b4 * 32 + rs) * XS + gk];
      else
        xv = make_float4(0.f, 0.f, 0.f, 0.f);
      *(float4*)&xs[rs * 36 + cs * 4] = xv;
    }
#pragma unroll
    for (int p = 0; p < 4; ++p) {  // stage w1: 128 rows, 4 passes
      int r = rs + p * 32;
      float4 wv;
      if (gk + 4 <= 36954) {
        F4 u = *(const F4*)&w1[(size_t)r * 36954 + gk];
        wv = make_float4(u.x, u.y, u.z, u.w);
      } else if (gk < 36954) {     // boundary tile (gk = 36952)
        wv.x = w1[(size_t)r * 36954 + gk];
        wv.y = (gk + 1 < 36954) ? w1[(size_t)r * 36954 + gk + 1] : 0.f;
        wv.z = 0.f; wv.w = 0.f;
      } else {
        wv = make_float4(0.f, 0.f, 0.f, 0.f);
      }
      *(float4*)&wsm[r * 36 + cs * 4] = wv;
    }
    __syncthreads();
#pragma unroll 1
    for (int kk = 0; kk < 32; kk += 4) {
      float4 xv[8], wv[2];
#pragma unroll
      for (int i = 0; i < 8; ++i)
        xv[i] = *(const float4*)&xs[(bq + 4 * i) * 36 + kk];
#pragma unroll
      for (int i = 0; i < 2; ++i)
        wv[i] = *(const float4*)&wsm[(jq + 64 * i) * 36 + kk];
#pragma unroll
      for (int bb = 0; bb < 8; ++bb)
#pragma unroll
        for (int jj = 0; jj < 2; ++jj) {
          acc[bb][jj] = fmaf(xv[bb].x, wv[jj].x, acc[bb][jj]);
          acc[bb][jj] = fmaf(xv[bb].y, wv[jj].y, acc[bb][jj]);
          acc[bb][jj] = fmaf(xv[bb].z, wv[jj].z, acc[bb][jj]);
          acc[bb][jj] = fmaf(xv[bb].w, wv[jj].w, acc[bb][jj]);
        }
    }
  }
  float* Pb = P + (size_t)kt * 16384;
#pragma unroll
  for (int bb = 0; bb < 8; ++bb)
#pragma unroll
    for (int jj = 0; jj < 2; ++jj)
      Pb[(b4 * 32 + bq + 4 * bb) * 128 + jq + 64 * jj] = acc[bb][jj];
}

// Reduce P over kt: h1s[b][j] = sum_kt P[kt][b][j] + b1[j].
// 32 loads in flight per thread (order-preserving: per-accumulator add
// sequences identical to the 4-accumulator loop), 256 blocks x 1 wave.
__global__ __launch_bounds__(64) void reduce_p_kernel(
    const float* __restrict__ P, const float* __restrict__ b1,
    float* __restrict__ h1s) {
  int idx = blockIdx.x * 64 + threadIdx.x;   // 0..16383
  int j = idx & 127;
  float a0 = 0.f, a1 = 0.f, a2 = 0.f, a3 = 0.f;
  int kt = 0;
  for (; kt + 31 < FC1_KT; kt += 32) {
    float v[32];
#pragma unroll
    for (int q = 0; q < 32; ++q)
      v[q] = P[(size_t)(kt + q) * 16384 + idx];
#pragma unroll
    for (int q = 0; q < 32; q += 4) {
      a0 += v[q]; a1 += v[q + 1]; a2 += v[q + 2]; a3 += v[q + 3];
    }
  }
  for (; kt + 3 < FC1_KT; kt += 4) {
    a0 += P[(size_t)(kt + 0) * 16384 + idx];
    a1 += P[(size_t)(kt + 1) * 16384 + idx];
    a2 += P[(size_t)(kt + 2) * 16384 + idx];
    a3 += P[(size_t)(kt + 3) * 16384 + idx];
  }
  for (; kt < FC1_KT; ++kt) a0 += P[(size_t)kt * 16384 + idx];
  h1s[idx] = ((a0 + a1) + (a2 + a3)) + b1[j];
}

// Recurrence: one block per batch row. w2 column in VGPRs (loaded once,
// 32 coalesced dwordx4); spk broadcast via LDS; w3 staged in LDS; layer3
// as 144-thread partials + 9-thread reduce. Critical path ~700 cyc/step.
__global__ __launch_bounds__(256, 1) void recur_kernel(
    const float* __restrict__ h1s,  // [128][128]
    const float4* __restrict__ w2q, // [32][256] float4 cols: w2q[k4*256+j]
    const float* __restrict__ b2,
    const float* __restrict__ w3,   // [9][256]
    const float* __restrict__ b3,
    float* __restrict__ out) {      // [128][9]
  int b = blockIdx.x;
  int t = threadIdx.x;
  __shared__ float spk1s[128];
  __shared__ float spk2s[256];
  __shared__ float w3s[9 * 256];
  __shared__ float part[9][16];
  float4 w2c[32];
#pragma unroll
  for (int k4 = 0; k4 < 32; ++k4) w2c[k4] = w2q[k4 * 256 + t];
  for (int i = t; i < 9 * 256; i += 256) w3s[i] = w3[i];
  float h1 = (t < 128) ? h1s[b * 128 + t] : 0.f;
  float mem1 = 0.f, syn1 = 0.f, mem2 = 0.f, syn2 = 0.f;
  float b2v = b2[t];
  float mem3 = 0.f, syn3 = 0.f, pot = 0.f;
  float b3v = (t < 9) ? b3[t] : 0.f;
  int j3 = t >> 4, p = t & 15;      // layer3 partial owners (t < 144)
  __syncthreads();                  // w3s ready

  for (int step = 0; step < 10; ++step) {
    if (t < 128) {
      syn1 = ALPHA * syn1 + h1;
      mem1 = BETA * mem1 + syn1;
      float s = (mem1 > 1.0f) ? 1.0f : 0.0f;
      mem1 -= s;
      spk1s[t] = s;
    }
    __syncthreads();
    float h2 = b2v;
#pragma unroll
    for (int k4 = 0; k4 < 32; ++k4) {
      float4 s = *(const float4*)&spk1s[k4 * 4];   // broadcast read
      h2 = fmaf(s.x, w2c[k4].x, h2);
      h2 = fmaf(s.y, w2c[k4].y, h2);
      h2 = fmaf(s.z, w2c[k4].z, h2);
      h2 = fmaf(s.w, w2c[k4].w, h2);
    }
    syn2 = ALPHA * syn2 + h2;
    mem2 = BETA * mem2 + syn2;
    float s2 = (mem2 > 1.0f) ? 1.0f : 0.0f;
    mem2 -= s2;
    spk2s[t] = s2;
    __syncthreads();
    if (t < 144) {
      float a = 0.f;
      const float* wr = &w3s[j3 * 256 + p * 16];
      const float* sp = &spk2s[p * 16];
#pragma unroll
      for (int e = 0; e < 16; ++e) a = fmaf(sp[e], wr[e], a);
      part[j3][p] = a;
    }
    __syncthreads();
    if (t < 9) {
      float a = b3v;
#pragma unroll
      for (int p2 = 0; p2 < 16; ++p2) a += part[t][p2];
      syn3 = ALPHA * syn3 + a;
      mem3 = BETA * mem3 + syn3;
      pot += mem3;
    }
  }
  if (t < 9) out[b * 9 + t] = pot * 0.1f;
}

extern "C" void kernel_launch(void* const* d_in, const int* in_sizes, int n_in,
                              void* d_out, int out_size, void* d_ws, size_t ws_size,
                              hipStream_t stream) {
  const float* state   = (const float*)d_in[0];
  const float* history = (const float*)d_in[1];
  const float* cw1 = (const float*)d_in[2];
  const float* cb1 = (const float*)d_in[3];
  const float* cw2 = (const float*)d_in[4];
  const float* cb2 = (const float*)d_in[5];
  const float* cw3 = (const float*)d_in[6];
  const float* cb3 = (const float*)d_in[7];
  const float* w1  = (const float*)d_in[8];
  const float* b1  = (const float*)d_in[9];
  const float* w2  = (const float*)d_in[10];
  const float* b2  = (const float*)d_in[11];
  const float* w3  = (const float*)d_in[12];
  const float* b3  = (const float*)d_in[13];
  float* out = (float*)d_out;
  char* ws = (char*)d_ws;

  // workspace (bytes), time-multiplexed:
  //  f1hl  [0, 49,561,600)              conv1 -> conv2  (hl-pair dwords)
  //    xb  [0, 18,923,520)              conv3 -> fc1    (f1hl dead)
  //  f2hl  [49,561,600, 71,712,768)     conv2 -> conv3  (hl-pair dwords)
  //    P   [49,561,600, 68,501,504)     fc1 -> reduce   (f2hl dead)
  //  small weights [71,712,768, 72,261,632)
  u32*   f1hl = (u32*)(ws + 0);
  float* xb   = (float*)(ws + 0);
  u32*   f2hl = (u32*)(ws + 49561600);
  float* P    = (float*)(ws + 49561600);
  f16* wf1h = (f16*)(ws + 71712768);   // 12,288
  f16* wf1l = (f16*)(ws + 71725056);   // 12,288
  f16* wf2h = (f16*)(ws + 71737344);   // 65,536
  f16* wf2l = (f16*)(ws + 71802880);   // 65,536
  f16* wf3h = (f16*)(ws + 71868416);   // 98,304 (padded K=768)
  f16* wf3l = (f16*)(ws + 71966720);   // 98,304
  float* w2q = (float*)(ws + 72065024);  // 131,072
  float* h1s = (float*)(ws + 72196096);  // 65,536 (end 72,261,632)

  prep_weights_kernel<<<192, 256, 0, stream>>>(cw1, cw2, cw3, w2,
                                               wf1h, wf1l, wf2h, wf2l,
                                               wf3h, wf3l, w2q);
  // conv1: 224x224 -> 55x55(3025), OC=32, NPB=256, 512 threads (r19)
  conv1_kernel<<<dim3(12, 128), 512, 0, stream>>>(state, wf1h, wf1l, cb1, f1hl);
  // conv2: IC=32,KH=4,KWP=4,KWV=4,S=2, 55x55 -> 26x26(676), OC=64, NPB=128
  convhl_kernel<32, 4, 4, 4, 2, 55, 55, 26, 676, 64, 128, false>
      <<<dim3(6, 128), 512, 0, stream>>>(f1hl, wf2h, wf2l, cb2, (void*)f2hl);
  // conv3: IC=64,KH=3,KWP=4,KWV=3,S=1, 26x26 -> 24x24(576), OC=64, NPB=128 -> x
  convhl_kernel<64, 3, 4, 3, 1, 26, 26, 24, 576, 64, 128, true>
      <<<dim3(5, 128), 512, 0, stream>>>(f2hl, wf3h, wf3l, cb3, (void*)xb);
  histpack_kernel<<<48, 256, 0, stream>>>(history, xb);
  fc1_kernel<<<FC1_KT * 4, 256, 0, stream>>>(xb, w1, P);
  reduce_p_kernel<<<256, 64, 0, stream>>>(P, b1, h1s);
  recur_kernel<<<128, 256, 0, stream>>>(h1s, (const float4*)w2q, b2, w3, b3, out);
}

// Round 15
// 301.961 us; speedup vs baseline: 1.3178x; 1.0081x over previous
//
#include <hip/hip_runtime.h>

#define ALPHA 0.9f
#define BETA  0.8f
#define XS 36960   // padded row stride for x

typedef _Float16 f16;
typedef _Float16 f16x8 __attribute__((ext_vector_type(8)));
typedef float f32x4 __attribute__((ext_vector_type(4)));
typedef unsigned int u32;

// 16B load at only-4B-known alignment (w1 rows stride 36954 floats -> odd
// rows are 8B-aligned). Backend emits unaligned wide loads; same bytes.
struct F4 { float x, y, z, w; };   // alignof = 4

// async global->LDS DMA, 16B per lane: per-lane global src, wave-uniform LDS
// base + lane*16 dest (m97 pattern).
#define GLOAD_LDS16(gsrc, ldst)                                        \
  __builtin_amdgcn_global_load_lds(                                    \
      (const __attribute__((address_space(1))) void*)(gsrc),           \
      (__attribute__((address_space(3))) void*)(ldst), 16, 0, 0)

// de-interleave (h,l)-pair dwords: hpair = h1<<16|h0, lpair = l1<<16|l0
__device__ inline u32 hpair(u32 d0, u32 d1) {
#if __has_builtin(__builtin_amdgcn_perm)
  return __builtin_amdgcn_perm(d1, d0, 0x05040100u);
#else
  return (d0 & 0xffffu) | (d1 << 16);
#endif
}
__device__ inline u32 lpair(u32 d0, u32 d1) {
#if __has_builtin(__builtin_amdgcn_perm)
  return __builtin_amdgcn_perm(d1, d0, 0x07060302u);
#else
  return (d0 >> 16) | (d1 & 0xffff0000u);
#endif
}

// split fp32 -> packed (h,l) f16-pair dword (exact same h/l values as the
// old consumer-side split: h=f16(v), l=f16(v-h))
__device__ inline u32 pack_hl(float v) {
  f16 h = (f16)v;
  f16 l = (f16)(v - (float)h);
  return (u32)__builtin_bit_cast(unsigned short, h) |
         ((u32)__builtin_bit_cast(unsigned short, l) << 16);
}

// ---------------------------------------------------------------------------
// state: 128x3x224x224  conv1 32x3x8x8 s4 -> f1hl (hl-pair) 128x32x55x55
// f1hl -> conv2 64x32x4x4 s2 -> f2hl (hl-pair) 128x64x26x26
// f2hl -> conv3 64x64x3x3 s1 -> x rows fp32 (36864 + 90 history, pad 36960)
// Convs: split-f16 MFMA (hi+lo, 3 MFMAs/product, fp32-quality: absmax 0.0).
// r21: conv1 B-staging deduplicated -- stage the 24 unique input ROWS per
//   kt (4 filter-rows x 6 oh, one 896B contiguous gload_lds each; 16B row
//   pad -> conflict-free), fragments = two aligned float4 reads at ow*16.
//   Was 32KB/kt with ~1.5-2x chunk duplication and 4x256B scattered runs;
//   now 24KB/kt fully streaming. Fragment floats bitwise identical.
//   Rest = r20 verbatim (304.4us best).
// r24: identical resubmission (rounds 12-14 were GPUAcquisitionTimeout,
//   kernel never ran).
// ---------------------------------------------------------------------------

// Split conv weights into f16 hi/lo pairs; conv3 padded [oc][c][kh][4]
// (kw=3 -> 0). Repack w2 (256x128) -> w2q[k4][j] float4 columns.
__global__ __launch_bounds__(256) void prep_weights_kernel(
    const float* __restrict__ cw1, const float* __restrict__ cw2,
    const float* __restrict__ cw3, const float* __restrict__ w2,
    f16* __restrict__ w1h, f16* __restrict__ w1l,
    f16* __restrict__ w2h, f16* __restrict__ w2l,
    f16* __restrict__ w3h, f16* __restrict__ w3l,
    float* __restrict__ w2q) {
  int i = blockIdx.x * 256 + threadIdx.x;   // grid covers 49152
  if (i < 6144)  { float v = cw1[i]; f16 h = (f16)v; w1h[i] = h; w1l[i] = (f16)(v - (float)h); }
  if (i < 32768) { float v = cw2[i]; f16 h = (f16)v; w2h[i] = h; w2l[i] = (f16)(v - (float)h); }
  if (i < 49152) {
    int oc = i / 768, r = i % 768;
    int c = r / 12, rr = r % 12, kh = rr >> 2, kw = rr & 3;
    float v = (kw < 3) ? cw3[oc * 576 + c * 9 + kh * 3 + kw] : 0.f;
    f16 h = (f16)v; w3h[i] = h; w3l[i] = (f16)(v - (float)h);
  }
  if (i < 32768) {   // w2[j][k] -> w2q[(k4*256 + j)*4 + e]
    int j = i >> 7, k = i & 127;
    w2q[((k >> 2) * 256 + j) * 4 + (k & 3)] = w2[i];
  }
}

// ---------------------------------------------------------------------------
// conv1 (r21): 512 threads / 8 waves / NPB=256. MFMA layouts (HW-verified):
// A[m=lane&15][k=quad*8+j], B[k=quad*8+j][n=lane&15], C col=lane&15
// row=quad*4+reg. k = kt*32 + quad*8 + kw: quad selects filter-row
// gr = kt*4+quad (c=gr>>3, kh=gr&7), j = kw 0..7.
// B storage: whole input rows. LDS row region rowid = quad*6 + ohl
// (ohl = oh - oh0, 0..5), 260 floats (224 data + pad; stride 1040B ->
// quad bank offsets 24q%32, distinct). Stage: wave w DMAs rowids
// {3w,3w+1,3w+2}, lane l -> bytes l*16 (src iw = min(l*4,220); lanes 56-63
// duplicate the tail chunk into pad, never read).
// Fragment for pos (oh,ow): floats [4ow, 4ow+8) of row (quad,ohl) -- two
// aligned float4 at off ow*4 and ow*4+4 (max 224 <= 260, in data).
// Values bitwise identical to r20's chunk staging.
// ---------------------------------------------------------------------------
__global__ __launch_bounds__(512) void conv1_kernel(
    const float* __restrict__ in, const f16* __restrict__ wh,
    const f16* __restrict__ wl, const float* __restrict__ bias,
    u32* __restrict__ out) {
  constexpr int K = 192, KCH = 6, OW = 55, OHW = 3025, NPB = 256;
  constexpr int RSTRIDE = 260;               // floats per LDS row region
  __shared__ __attribute__((aligned(16))) f16 Ah[2 * 512], Al[2 * 512]; // 4KB
  __shared__ __attribute__((aligned(16))) float Bf[24 * RSTRIDE];      // ~25KB

  const int n = blockIdx.y, pos0 = blockIdx.x * NPB;
  const int t = threadIdx.x;                 // 0..511
  const int w = t >> 6, lane = t & 63, quad = lane >> 4, l16 = lane & 15;
  const float* __restrict__ inb = in + (size_t)n * 3 * 224 * 224;
  const int oh0 = pos0 / OW;

  // staging: wave w stages rowids 3w..3w+2; per-lane iw (dup tail in pad)
  const int siw = (lane * 4 > 220) ? 220 : lane * 4;

  // A slot (t<128): oc am, k offset ak
  const int am = (t >> 6) * 16 + (t & 15);
  const int ak = ((t >> 4) & 3) * 8;

  // fragment invariants: per ntl, pos -> (ohl, ow) -> LDS float offset
  int posv[2], fa[2];
#pragma unroll
  for (int ntl = 0; ntl < 2; ++ntl) {
    int pos = pos0 + (w * 2 + ntl) * 16 + l16;
    posv[ntl] = pos;
    if (pos > OHW - 1) pos = OHW - 1;        // clamp (store masked later)
    int oh = pos / OW, ow = pos - oh * OW;
    fa[ntl] = (quad * 6 + (oh - oh0)) * RSTRIDE + ow * 4;
  }

  f32x4 acc[2][2] = {};

  for (int kt = 0; kt < KCH; ++kt) {
    __syncthreads();
    if (t < 128) {   // stage weights (tiny, plain)
      *(f16x8*)&Ah[t * 8] = *(const f16x8*)&wh[am * K + kt * 32 + ak];
      *(f16x8*)&Al[t * 8] = *(const f16x8*)&wl[am * K + kt * 32 + ak];
    }
    {  // async B staging: 3 row-DMAs per wave (24 rows total)
#pragma unroll
      for (int i = 0; i < 3; ++i) {
        int rowid = w * 3 + i;               // 0..23
        int r = rowid / 6, ohl = rowid % 6;  // filter-row, oh offset
        int gr = kt * 4 + r;
        int c = gr >> 3, kh = gr & 7;
        int oh = oh0 + ohl; if (oh > 54) oh = 54;   // clamp (never read)
        const float* src = inb + c * 50176 + (oh * 4 + kh) * 224 + siw;
        GLOAD_LDS16(src, &Bf[rowid * RSTRIDE]);
      }
    }
    __syncthreads();   // drains vmcnt: B in LDS, A visible

    f16x8 ah0 = *(const f16x8*)&Ah[0 * 512 + lane * 8];
    f16x8 ah1 = *(const f16x8*)&Ah[1 * 512 + lane * 8];
    f16x8 al0 = *(const f16x8*)&Al[0 * 512 + lane * 8];
    f16x8 al1 = *(const f16x8*)&Al[1 * 512 + lane * 8];
    f16x8 bh[2], bl[2];
#pragma unroll
    for (int ntl = 0; ntl < 2; ++ntl) {
      float4 v0 = *(const float4*)&Bf[fa[ntl]];
      float4 v1 = *(const float4*)&Bf[fa[ntl] + 4];
      float vv[8] = {v0.x, v0.y, v0.z, v0.w, v1.x, v1.y, v1.z, v1.w};
#pragma unroll
      for (int e = 0; e < 8; ++e) {
        f16 h = (f16)vv[e];
        bh[ntl][e] = h;
        bl[ntl][e] = (f16)(vv[e] - (float)h);
      }
    }
    acc[0][0] = __builtin_amdgcn_mfma_f32_16x16x32_f16(ah0, bh[0], acc[0][0], 0, 0, 0);
    acc[0][0] = __builtin_amdgcn_mfma_f32_16x16x32_f16(ah0, bl[0], acc[0][0], 0, 0, 0);
    acc[0][0] = __builtin_amdgcn_mfma_f32_16x16x32_f16(al0, bh[0], acc[0][0], 0, 0, 0);
    acc[1][0] = __builtin_amdgcn_mfma_f32_16x16x32_f16(ah1, bh[0], acc[1][0], 0, 0, 0);
    acc[1][0] = __builtin_amdgcn_mfma_f32_16x16x32_f16(ah1, bl[0], acc[1][0], 0, 0, 0);
    acc[1][0] = __builtin_amdgcn_mfma_f32_16x16x32_f16(al1, bh[0], acc[1][0], 0, 0, 0);
    acc[0][1] = __builtin_amdgcn_mfma_f32_16x16x32_f16(ah0, bh[1], acc[0][1], 0, 0, 0);
    acc[0][1] = __builtin_amdgcn_mfma_f32_16x16x32_f16(ah0, bl[1], acc[0][1], 0, 0, 0);
    acc[0][1] = __builtin_amdgcn_mfma_f32_16x16x32_f16(al0, bh[1], acc[0][1], 0, 0, 0);
    acc[1][1] = __builtin_amdgcn_mfma_f32_16x16x32_f16(ah1, bh[1], acc[1][1], 0, 0, 0);
    acc[1][1] = __builtin_amdgcn_mfma_f32_16x16x32_f16(ah1, bl[1], acc[1][1], 0, 0, 0);
    acc[1][1] = __builtin_amdgcn_mfma_f32_16x16x32_f16(al1, bh[1], acc[1][1], 0, 0, 0);
  }

#pragma unroll
  for (int mtl = 0; mtl < 2; ++mtl)
#pragma unroll
    for (int ntl = 0; ntl < 2; ++ntl)
#pragma unroll
      for (int r = 0; r < 4; ++r) {
        int oc  = mtl * 16 + quad * 4 + r;
        int pos = posv[ntl];
        if (pos < OHW) {
          float v = acc[mtl][ntl][r] + bias[oc];
          v = v > 0.f ? v : 0.f;
          out[((size_t)n * 32 + oc) * OHW + pos] = pack_hl(v);
        }
      }
}

// ---------------------------------------------------------------------------
// conv2/conv3 (r20: NPB=128, 512 threads, 8 waves): input packed (h,l)-pair
// dwords -> staging is a pure dword copy (8 independent loads/thread, no
// conversion), de-interleave at fragment read via v_perm. OC=64: MTILES=4,
// NTILES=NPB/16=8. Waves: woc = w&1 (oc half), wpos = w>>1 (pos pair 0..3).
// B slot s = t (0..511): npos = (s>>6)*16 + (s&15). A staged by t<256.
// LDS 24KB. Per-output math and k-order identical to the 256-thread form.
// ---------------------------------------------------------------------------
template<int IC, int KH, int KWP, int KWV, int S, int IH, int IW,
         int OW, int OHW, int OC, int NPB, bool OUT_X>
__global__ __launch_bounds__(NPB * 4) void convhl_kernel(
    const u32* __restrict__ in, const f16* __restrict__ wh,
    const f16* __restrict__ wl, const float* __restrict__ bias,
    void* __restrict__ outv) {
  constexpr int K = IC * KH * KWP;      // 512 / 768
  constexpr int KCH = K / 32;           // 16 / 24
  constexpr int BS = NPB * 4;           // block size: 512
  __shared__ __attribute__((aligned(16))) f16 Ah[4 * 512], Al[4 * 512]; // 8KB
  __shared__ __attribute__((aligned(16))) u32 Bhl[2][BS * 4];           // 16KB

  const int n = blockIdx.y, pos0 = blockIdx.x * NPB;
  const int t = threadIdx.x;
  const int w = t >> 6, lane = t & 63, quad = lane >> 4, l16 = lane & 15;
  const int woc = w & 1, wpos = w >> 1;   // wpos 0..3
  const u32* __restrict__ inb = in + (size_t)n * IC * IH * IW;

  // B slot s = t: npos = (t>>6)*16 + (t&15); k-rows kt*8 + rq + half
  int pos = pos0 + (t >> 6) * 16 + (t & 15);
  if (pos > OHW - 1) pos = OHW - 1;      // clamp (store masked later)
  int oh = pos / OW, ow = pos - oh * OW;
  const int ohS = oh * S, owS = ow * S;
  const int rq = ((t >> 4) & 3) * 2;
  const int am = (t >> 6) * 16 + (t & 15);   // valid for t<256
  const int ak = ((t >> 4) & 3) * 8;

  int posv[2];
#pragma unroll
  for (int ntl = 0; ntl < 2; ++ntl)
    posv[ntl] = pos0 + (wpos * 2 + ntl) * 16 + l16;

  f32x4 acc[2][2] = {};

  for (int kt = 0; kt < KCH; ++kt) {
    __syncthreads();
    if (t < 256) {   // stage weights: 8 consecutive k for one oc
      *(f16x8*)&Ah[t * 8] = *(const f16x8*)&wh[am * K + kt * 32 + ak];
      *(f16x8*)&Al[t * 8] = *(const f16x8*)&wl[am * K + kt * 32 + ak];
    }
    // stage B: pure hl-dword gather, 4 dwords per half
#pragma unroll
    for (int half = 0; half < 2; ++half) {
      int row = kt * 8 + rq + half;
      int c = row / KH, kh = row - c * KH;
      const u32* p = inb + ((size_t)c * IH + ohS + kh) * IW + owS;
      uint4 d;
      d.x = p[0]; d.y = p[1]; d.z = p[2];
      d.w = (KWV < KWP) ? 0u : p[3];       // conv3: padded kw=3 -> 0
      *(uint4*)&Bhl[half][t * 4] = d;
    }
    __syncthreads();

    f16x8 ah0 = *(const f16x8*)&Ah[(woc * 2 + 0) * 512 + lane * 8];
    f16x8 ah1 = *(const f16x8*)&Ah[(woc * 2 + 1) * 512 + lane * 8];
    f16x8 al0 = *(const f16x8*)&Al[(woc * 2 + 0) * 512 + lane * 8];
    f16x8 al1 = *(const f16x8*)&Al[(woc * 2 + 1) * 512 + lane * 8];
    f16x8 bh[2], bl[2];
#pragma unroll
    for (int ntl = 0; ntl < 2; ++ntl) {
      int sl = ((wpos * 2 + ntl) * 64 + lane) * 4;
      uint4 q0 = *(const uint4*)&Bhl[0][sl];
      uint4 q1 = *(const uint4*)&Bhl[1][sl];
      uint4 hv, lv;
      hv.x = hpair(q0.x, q0.y); lv.x = lpair(q0.x, q0.y);
      hv.y = hpair(q0.z, q0.w); lv.y = lpair(q0.z, q0.w);
      hv.z = hpair(q1.x, q1.y); lv.z = lpair(q1.x, q1.y);
      hv.w = hpair(q1.z, q1.w); lv.w = lpair(q1.z, q1.w);
      bh[ntl] = __builtin_bit_cast(f16x8, hv);
      bl[ntl] = __builtin_bit_cast(f16x8, lv);
    }
    acc[0][0] = __builtin_amdgcn_mfma_f32_16x16x32_f16(ah0, bh[0], acc[0][0], 0, 0, 0);
    acc[0][0] = __builtin_amdgcn_mfma_f32_16x16x32_f16(ah0, bl[0], acc[0][0], 0, 0, 0);
    acc[0][0] = __builtin_amdgcn_mfma_f32_16x16x32_f16(al0, bh[0], acc[0][0], 0, 0, 0);
    acc[1][0] = __builtin_amdgcn_mfma_f32_16x16x32_f16(ah1, bh[0], acc[1][0], 0, 0, 0);
    acc[1][0] = __builtin_amdgcn_mfma_f32_16x16x32_f16(ah1, bl[0], acc[1][0], 0, 0, 0);
    acc[1][0] = __builtin_amdgcn_mfma_f32_16x16x32_f16(al1, bh[0], acc[1][0], 0, 0, 0);
    acc[0][1] = __builtin_amdgcn_mfma_f32_16x16x32_f16(ah0, bh[1], acc[0][1], 0, 0, 0);
    acc[0][1] = __builtin_amdgcn_mfma_f32_16x16x32_f16(ah0, bl[1], acc[0][1], 0, 0, 0);
    acc[0][1] = __builtin_amdgcn_mfma_f32_16x16x32_f16(al0, bh[1], acc[0][1], 0, 0, 0);
    acc[1][1] = __builtin_amdgcn_mfma_f32_16x16x32_f16(ah1, bh[1], acc[1][1], 0, 0, 0);
    acc[1][1] = __builtin_amdgcn_mfma_f32_16x16x32_f16(ah1, bl[1], acc[1][1], 0, 0, 0);
    acc[1][1] = __builtin_amdgcn_mfma_f32_16x16x32_f16(al1, bh[1], acc[1][1], 0, 0, 0);
  }

#pragma unroll
  for (int mtl = 0; mtl < 2; ++mtl)
#pragma unroll
    for (int ntl = 0; ntl < 2; ++ntl)
#pragma unroll
      for (int r = 0; r < 4; ++r) {
        int oc = (woc * 2 + mtl) * 16 + quad * 4 + r;
        int p2 = posv[ntl];
        if (p2 < OHW) {
          float v = acc[mtl][ntl][r] + bias[oc];
          v = v > 0.f ? v : 0.f;
          if constexpr (OUT_X)
            ((float*)outv)[(size_t)n * XS + oc * OHW + p2] = v;
          else
            ((u32*)outv)[((size_t)n * OC + oc) * OHW + p2] = pack_hl(v);
        }
      }
}

// history -> x[:, 36864:36954], zero the pad to 36960
__global__ __launch_bounds__(256) void histpack_kernel(
    const float* __restrict__ h, float* __restrict__ x) {
  int i = blockIdx.x * 256 + threadIdx.x;
  if (i < 128 * 96) {
    int n = i / 96, k = i % 96;
    x[(size_t)n * XS + 36864 + k] = (k < 90) ? h[n * 90 + k] : 0.f;
  }
}

// FC1 (fp32): register-blocked split-K GEMM. r18: 32b x 128j tile per block
// (batch split x4, grid FC1_KT*4) for occupancy; K-chunking UNchanged so
// every (b,j,kt) partial keeps its unbroken kk FMA chain -> P bitwise
// identical to the 128b-tile version. Reads w1 directly (align-4 loads,
// explicit zeros at the K boundary).
#define FC1_KT 289
__global__ __launch_bounds__(256) void fc1_kernel(
    const float* __restrict__ x, const float* __restrict__ w1,
    float* __restrict__ P) {
  int kt = blockIdx.x >> 2;       // 0..288
  int b4 = blockIdx.x & 3;        // batch quarter (32 rows)
  int t  = threadIdx.x;
  int bq = t & 3, jq = t >> 2;    // bq 0..3, jq 0..63
  __shared__ float xs[32 * 36];
  __shared__ float wsm[128 * 36];
  float acc[8][2];
#pragma unroll
  for (int bb = 0; bb < 8; ++bb)
#pragma unroll
    for (int jj = 0; jj < 2; ++jj) acc[bb][jj] = 0.f;

  int cs = t & 7;          // float4 column for staging (0..7)
  int rs = t >> 3;         // row for staging (0..31)
#pragma unroll 1
  for (int s = 0; s < 4; ++s) {
    int k0 = kt * 128 + s * 32;
    int gk = k0 + cs * 4;
    __syncthreads();
    {  // stage x: 32 rows (global b4*32 + rs), one float4/thread
      float4 xv;
      if (gk < 36954)      // x pad [36954,36960) is zeros -> float4 safe
        xv = *(const float4*)&x[(size_t)(b4 * 32 + rs) * XS + gk];
      else
        xv = make_float4(0.f, 0.f, 0.f, 0.f);
      *(float4*)&xs[rs * 36 + cs * 4] = xv;
    }
#pragma unroll
    for (int p = 0; p < 4; ++p) {  // stage w1: 128 rows, 4 passes
      int r = rs + p * 32;
      float4 wv;
      if (gk + 4 <= 36954) {
        F4 u = *(const F4*)&w1[(size_t)r * 36954 + gk];
        wv = make_float4(u.x, u.y, u.z, u.w);
      } else if (gk < 36954) {     // boundary tile (gk = 36952)
        wv.x = w1[(size_t)r * 36954 + gk];
        wv.y = (gk + 1 < 36954) ? w1[(size_t)r * 36954 + gk + 1] : 0.f;
        wv.z = 0.f; wv.w = 0.f;
      } else {
        wv = make_float4(0.f, 0.f, 0.f, 0.f);
      }
      *(float4*)&wsm[r * 36 + cs * 4] = wv;
    }
    __syncthreads();
#pragma unroll 1
    for (int kk = 0; kk < 32; kk += 4) {
      float4 xv[8], wv[2];
#pragma unroll
      for (int i = 0; i < 8; ++i)
        xv[i] = *(const float4*)&xs[(bq + 4 * i) * 36 + kk];
#pragma unroll
      for (int i = 0; i < 2; ++i)
        wv[i] = *(const float4*)&wsm[(jq + 64 * i) * 36 + kk];
#pragma unroll
      for (int bb = 0; bb < 8; ++bb)
#pragma unroll
        for (int jj = 0; jj < 2; ++jj) {
          acc[bb][jj] = fmaf(xv[bb].x, wv[jj].x, acc[bb][jj]);
          acc[bb][jj] = fmaf(xv[bb].y, wv[jj].y, acc[bb][jj]);
          acc[bb][jj] = fmaf(xv[bb].z, wv[jj].z, acc[bb][jj]);
          acc[bb][jj] = fmaf(xv[bb].w, wv[jj].w, acc[bb][jj]);
        }
    }
  }
  float* Pb = P + (size_t)kt * 16384;
#pragma unroll
  for (int bb = 0; bb < 8; ++bb)
#pragma unroll
    for (int jj = 0; jj < 2; ++jj)
      Pb[(b4 * 32 + bq + 4 * bb) * 128 + jq + 64 * jj] = acc[bb][jj];
}

// Reduce P over kt: h1s[b][j] = sum_kt P[kt][b][j] + b1[j].
// 32 loads in flight per thread (order-preserving: per-accumulator add
// sequences identical to the 4-accumulator loop), 256 blocks x 1 wave.
__global__ __launch_bounds__(64) void reduce_p_kernel(
    const float* __restrict__ P, const float* __restrict__ b1,
    float* __restrict__ h1s) {
  int idx = blockIdx.x * 64 + threadIdx.x;   // 0..16383
  int j = idx & 127;
  float a0 = 0.f, a1 = 0.f, a2 = 0.f, a3 = 0.f;
  int kt = 0;
  for (; kt + 31 < FC1_KT; kt += 32) {
    float v[32];
#pragma unroll
    for (int q = 0; q < 32; ++q)
      v[q] = P[(size_t)(kt + q) * 16384 + idx];
#pragma unroll
    for (int q = 0; q < 32; q += 4) {
      a0 += v[q]; a1 += v[q + 1]; a2 += v[q + 2]; a3 += v[q + 3];
    }
  }
  for (; kt + 3 < FC1_KT; kt += 4) {
    a0 += P[(size_t)(kt + 0) * 16384 + idx];
    a1 += P[(size_t)(kt + 1) * 16384 + idx];
    a2 += P[(size_t)(kt + 2) * 16384 + idx];
    a3 += P[(size_t)(kt + 3) * 16384 + idx];
  }
  for (; kt < FC1_KT; ++kt) a0 += P[(size_t)kt * 16384 + idx];
  h1s[idx] = ((a0 + a1) + (a2 + a3)) + b1[j];
}

// Recurrence: one block per batch row. w2 column in VGPRs (loaded once,
// 32 coalesced dwordx4); spk broadcast via LDS; w3 staged in LDS; layer3
// as 144-thread partials + 9-thread reduce. Critical path ~700 cyc/step.
__global__ __launch_bounds__(256, 1) void recur_kernel(
    const float* __restrict__ h1s,  // [128][128]
    const float4* __restrict__ w2q, // [32][256] float4 cols: w2q[k4*256+j]
    const float* __restrict__ b2,
    const float* __restrict__ w3,   // [9][256]
    const float* __restrict__ b3,
    float* __restrict__ out) {      // [128][9]
  int b = blockIdx.x;
  int t = threadIdx.x;
  __shared__ float spk1s[128];
  __shared__ float spk2s[256];
  __shared__ float w3s[9 * 256];
  __shared__ float part[9][16];
  float4 w2c[32];
#pragma unroll
  for (int k4 = 0; k4 < 32; ++k4) w2c[k4] = w2q[k4 * 256 + t];
  for (int i = t; i < 9 * 256; i += 256) w3s[i] = w3[i];
  float h1 = (t < 128) ? h1s[b * 128 + t] : 0.f;
  float mem1 = 0.f, syn1 = 0.f, mem2 = 0.f, syn2 = 0.f;
  float b2v = b2[t];
  float mem3 = 0.f, syn3 = 0.f, pot = 0.f;
  float b3v = (t < 9) ? b3[t] : 0.f;
  int j3 = t >> 4, p = t & 15;      // layer3 partial owners (t < 144)
  __syncthreads();                  // w3s ready

  for (int step = 0; step < 10; ++step) {
    if (t < 128) {
      syn1 = ALPHA * syn1 + h1;
      mem1 = BETA * mem1 + syn1;
      float s = (mem1 > 1.0f) ? 1.0f : 0.0f;
      mem1 -= s;
      spk1s[t] = s;
    }
    __syncthreads();
    float h2 = b2v;
#pragma unroll
    for (int k4 = 0; k4 < 32; ++k4) {
      float4 s = *(const float4*)&spk1s[k4 * 4];   // broadcast read
      h2 = fmaf(s.x, w2c[k4].x, h2);
      h2 = fmaf(s.y, w2c[k4].y, h2);
      h2 = fmaf(s.z, w2c[k4].z, h2);
      h2 = fmaf(s.w, w2c[k4].w, h2);
    }
    syn2 = ALPHA * syn2 + h2;
    mem2 = BETA * mem2 + syn2;
    float s2 = (mem2 > 1.0f) ? 1.0f : 0.0f;
    mem2 -= s2;
    spk2s[t] = s2;
    __syncthreads();
    if (t < 144) {
      float a = 0.f;
      const float* wr = &w3s[j3 * 256 + p * 16];
      const float* sp = &spk2s[p * 16];
#pragma unroll
      for (int e = 0; e < 16; ++e) a = fmaf(sp[e], wr[e], a);
      part[j3][p] = a;
    }
    __syncthreads();
    if (t < 9) {
      float a = b3v;
#pragma unroll
      for (int p2 = 0; p2 < 16; ++p2) a += part[t][p2];
      syn3 = ALPHA * syn3 + a;
      mem3 = BETA * mem3 + syn3;
      pot += mem3;
    }
  }
  if (t < 9) out[b * 9 + t] = pot * 0.1f;
}

extern "C" void kernel_launch(void* const* d_in, const int* in_sizes, int n_in,
                              void* d_out, int out_size, void* d_ws, size_t ws_size,
                              hipStream_t stream) {
  const float* state   = (const float*)d_in[0];
  const float* history = (const float*)d_in[1];
  const float* cw1 = (const float*)d_in[2];
  const float* cb1 = (const float*)d_in[3];
  const float* cw2 = (const float*)d_in[4];
  const float* cb2 = (const float*)d_in[5];
  const float* cw3 = (const float*)d_in[6];
  const float* cb3 = (const float*)d_in[7];
  const float* w1  = (const float*)d_in[8];
  const float* b1  = (const float*)d_in[9];
  const float* w2  = (const float*)d_in[10];
  const float* b2  = (const float*)d_in[11];
  const float* w3  = (const float*)d_in[12];
  const float* b3  = (const float*)d_in[13];
  float* out = (float*)d_out;
  char* ws = (char*)d_ws;

  // workspace (bytes), time-multiplexed:
  //  f1hl  [0, 49,561,600)              conv1 -> conv2  (hl-pair dwords)
  //    xb  [0, 18,923,520)              conv3 -> fc1    (f1hl dead)
  //  f2hl  [49,561,600, 71,712,768)     conv2 -> conv3  (hl-pair dwords)
  //    P   [49,561,600, 68,501,504)     fc1 -> reduce   (f2hl dead)
  //  small weights [71,712,768, 72,261,632)
  u32*   f1hl = (u32*)(ws + 0);
  float* xb   = (float*)(ws + 0);
  u32*   f2hl = (u32*)(ws + 49561600);
  float* P    = (float*)(ws + 49561600);
  f16* wf1h = (f16*)(ws + 71712768);   // 12,288
  f16* wf1l = (f16*)(ws + 71725056);   // 12,288
  f16* wf2h = (f16*)(ws + 71737344);   // 65,536
  f16* wf2l = (f16*)(ws + 71802880);   // 65,536
  f16* wf3h = (f16*)(ws + 71868416);   // 98,304 (padded K=768)
  f16* wf3l = (f16*)(ws + 71966720);   // 98,304
  float* w2q = (float*)(ws + 72065024);  // 131,072
  float* h1s = (float*)(ws + 72196096);  // 65,536 (end 72,261,632)

  prep_weights_kernel<<<192, 256, 0, stream>>>(cw1, cw2, cw3, w2,
                                               wf1h, wf1l, wf2h, wf2l,
                                               wf3h, wf3l, w2q);
  // conv1: 224x224 -> 55x55(3025), OC=32, NPB=256, 512 threads (r21 rows)
  conv1_kernel<<<dim3(12, 128), 512, 0, stream>>>(state, wf1h, wf1l, cb1, f1hl);
  // conv2: IC=32,KH=4,KWP=4,KWV=4,S=2, 55x55 -> 26x26(676), OC=64, NPB=128
  convhl_kernel<32, 4, 4, 4, 2, 55, 55, 26, 676, 64, 128, false>
      <<<dim3(6, 128), 512, 0, stream>>>(f1hl, wf2h, wf2l, cb2, (void*)f2hl);
  // conv3: IC=64,KH=3,KWP=4,KWV=3,S=1, 26x26 -> 24x24(576), OC=64, NPB=128 -> x
  convhl_kernel<64, 3, 4, 3, 1, 26, 26, 24, 576, 64, 128, true>
      <<<dim3(5, 128), 512, 0, stream>>>(f2hl, wf3h, wf3l, cb3, (void*)xb);
  histpack_kernel<<<48, 256, 0, stream>>>(history, xb);
  fc1_kernel<<<FC1_KT * 4, 256, 0, stream>>>(xb, w1, P);
  reduce_p_kernel<<<256, 64, 0, stream>>>(P, b1, h1s);
  recur_kernel<<<128, 256, 0, stream>>>(h1s, (const float4*)w2q, b2, w3, b3, out);
}